// Round 5
// baseline (306.948 us; speedup 1.0000x reference)
//
#include <hip/hip_runtime.h>

// Problem constants (B, L_IN, D) = (4, 4096, 1024)
#define BB 4
#define LL 4096
#define DD 1024
#define SS 128  // number of chunks in the scan
#define TT 32   // chunk length (SS*TT == LL)

typedef __attribute__((ext_vector_type(4))) float  floatx4;
typedef __attribute__((ext_vector_type(8))) short  shortx8;

static __device__ __forceinline__ unsigned short f2bf(float f) {
    unsigned int u = __float_as_uint(f);
    u += 0x7fffu + ((u >> 16) & 1u);           // round-to-nearest-even
    return (unsigned short)(u >> 16);
}
static __device__ __forceinline__ float bf2f(unsigned short h) {
    return __uint_as_float(((unsigned int)h) << 16);
}

// ---------------- merged f32 -> bf16 cast (inputs + Wi + Wo) ----------------
#define NIN4 (BB * LL * DD / 4)          // 4194304
#define NW4  (2 * DD * DD / 4)           // 524288
__global__ void cast_all_kernel(const float4* __restrict__ s_in, ushort4* __restrict__ d_inb,
                                const float4* __restrict__ s_wi, ushort4* __restrict__ d_wib,
                                const float4* __restrict__ s_wo, ushort4* __restrict__ d_wob) {
    int i = blockIdx.x * blockDim.x + threadIdx.x;
    const float4* s; ushort4* d; int j;
    if (i < NIN4)                 { s = s_in; d = d_inb; j = i; }
    else if (i < NIN4 + NW4)      { s = s_wi; d = d_wib; j = i - NIN4; }
    else                          { s = s_wo; d = d_wob; j = i - NIN4 - NW4; }
    float4 v = s[j];
    ushort4 o;
    o.x = f2bf(v.x); o.y = f2bf(v.y); o.z = f2bf(v.z); o.w = f2bf(v.w);
    d[j] = o;
}

// ---------------- bf16 GEMM: C[M,N] = A[M,K] * B[N,K]^T + bias ----------------
// 256x256 tile, BK=64, 512 threads = 8 waves (2M x 4N), per-wave 128x64 output.
// READ-AHEAD 4-phase schedule (best measured r2 variant): each phase issues the
// NEXT phase's ds_reads AFTER its MFMA cluster, so read drain hides under MFMA
// + barrier; one raw s_barrier per phase; counted vmcnt(4) once per K-tile.
//
// Hazard proof (semantic, no timing assumptions). R(p) = reads pending at
// phase p top (issued end of p-1); S(p) = region staged in phase p.
//   R(ph1)={A0,B0}(cb)  R(ph2)={B1(cb)}  R(ph3)={A1(cb)}  R(ph4)={}
//   S(ph1)=B0(cb^1,t+1) S(ph2)=A0(cb,t+2) S(ph3)=B1(cb,t+2) S(ph4)=A1(cb,t+2)
// 1) S(p) ∩ R(p) = ∅ and S(p) ∩ R(p+1) = ∅ for all p.
// 2) Every S(p) overwriting a previously-read region is issued after a barrier
//    whose arrival implies all waves retired those reads via lgkmcnt(0).
// 3) vmcnt(4) before bar4 retires everything through S(ph1)=B0(t+1);
//    end-of-ph4 reads {A0,B0}(cb^1,t+1) are issued after bar4.
//
// LDS chunk swizzle (verified, 0 bank conflicts): within each 128-row
// half-tile, chunk q holds row=q>>3, k8=(q&7)^(row&7); reads XOR with r16&7.
template<int K, int NT, int EPI>
__global__ __launch_bounds__(512, 2)
void gemm256(const unsigned short* __restrict__ A,
             const unsigned short* __restrict__ B,
             const float* __restrict__ bias,
             void* __restrict__ Cp) {
    constexpr int N   = NT * 256;
    constexpr int NKT = K / 64;            // 16 or 32 here
    __shared__ __align__(16) short As[2][256 * 64];   // 64 KB
    __shared__ __align__(16) short Bs[2][256 * 64];   // 64 KB

    const int tid = threadIdx.x;
    const int blk = blockIdx.x;
    const int xcd = blk & 7;
    const int i2  = blk >> 3;
    const int tileM = ((i2 / NT) * 8 + xcd) * 256;
    const int tileN = (i2 % NT) * 256;

    const int lane   = tid & 63;
    const int wave   = tid >> 6;
    const int wave_m = wave >> 2;          // 0..1
    const int wave_n = wave & 3;           // 0..3
    const int r16    = lane & 15;
    const int quad   = lane >> 4;
    const int slotx  = r16 & 7;
    const int wmRow  = wave_m * 64 + r16;
    const int wnRow  = wave_n * 32 + r16;

    const int srow = tid >> 3;                         // 0..63
    const int scol = ((tid & 7) ^ (srow & 7)) * 8;     // pre-swizzled k offset (shorts)
    const int ldsChunkBase = (tid & ~63) * 8;          // shorts
    const size_t aOff = (size_t)(tileM + srow) * K + scol;
    const size_t bOff = (size_t)(tileN + srow) * K + scol;

    floatx4 acc[8][4] = {};
    shortx8 af[4][2], bf0v[2][2], bf1v[2][2];

#define GLL(SRC, DST) __builtin_amdgcn_global_load_lds( \
        (const __attribute__((address_space(1))) void*)(SRC), \
        (__attribute__((address_space(3))) void*)(DST), 16, 0, 0)
#define STAGE_A(BUF, H, KT) do { \
    GLL(A + aOff + (size_t)((H) * 128) * K + (KT) * 64,      &As[BUF][(H) * 8192 + ldsChunkBase]); \
    GLL(A + aOff + (size_t)((H) * 128 + 64) * K + (KT) * 64, &As[BUF][(H) * 8192 + 4096 + ldsChunkBase]); \
} while (0)
#define STAGE_B(BUF, H, KT) do { \
    GLL(B + bOff + (size_t)((H) * 128) * K + (KT) * 64,      &Bs[BUF][(H) * 8192 + ldsChunkBase]); \
    GLL(B + bOff + (size_t)((H) * 128 + 64) * K + (KT) * 64, &Bs[BUF][(H) * 8192 + 4096 + ldsChunkBase]); \
} while (0)
#define LOAD_A(BUF, MH) do { \
    _Pragma("unroll") for (int il = 0; il < 4; ++il) \
    _Pragma("unroll") for (int kk = 0; kk < 2; ++kk) \
        af[il][kk] = *(const shortx8*)&As[BUF][((MH) * 128 + wmRow + il * 16) * 64 + ((kk * 4 + quad) ^ slotx) * 8]; \
} while (0)
#define LOAD_B(BUF, NH, DST) do { \
    _Pragma("unroll") for (int jl = 0; jl < 2; ++jl) \
    _Pragma("unroll") for (int kk = 0; kk < 2; ++kk) \
        DST[jl][kk] = *(const shortx8*)&Bs[BUF][((NH) * 128 + wnRow + jl * 16) * 64 + ((kk * 4 + quad) ^ slotx) * 8]; \
} while (0)
#define MFMAQ(MH, NH, BF) do { \
    __builtin_amdgcn_s_setprio(1); \
    _Pragma("unroll") for (int kk = 0; kk < 2; ++kk) \
    _Pragma("unroll") for (int il = 0; il < 4; ++il) \
    _Pragma("unroll") for (int jl = 0; jl < 2; ++jl) \
        acc[(MH) * 4 + il][(NH) * 2 + jl] = __builtin_amdgcn_mfma_f32_16x16x32_bf16( \
            af[il][kk], BF[jl][kk], acc[(MH) * 4 + il][(NH) * 2 + jl], 0, 0, 0); \
    __builtin_amdgcn_s_setprio(0); \
} while (0)
#define BAR()  __builtin_amdgcn_s_barrier()
#define LGKM0() asm volatile("s_waitcnt lgkmcnt(0)" ::: "memory")

    // prologue: tile0 (A0,B0,B1,A1) + A0(1),B1(1),A1(1) = 14 GLLs
    STAGE_A(0, 0, 0);
    STAGE_B(0, 0, 0);
    STAGE_B(0, 1, 0);
    STAGE_A(0, 1, 0);
    STAGE_A(1, 0, 1);
    STAGE_B(1, 1, 1);
    STAGE_A(1, 1, 1);
    asm volatile("s_waitcnt vmcnt(6)" ::: "memory");   // tile0 landed; 6 in flight
    BAR();
    // pre-issue ph1(t=0) operands
    LOAD_A(0, 0);
    LOAD_B(0, 0, bf0v);

#pragma unroll 2
    for (int t = 0; t < NKT; ++t) {
        const int cb = t & 1;
        const int t1 = (t + 1 < NKT) ? t + 1 : NKT - 1;   // clamped tail: keeps
        const int t2 = (t + 2 < NKT) ? t + 2 : NKT - 1;   // vmcnt counts uniform
        // ---- phase 1: Q(0,0) ----
        BAR();
        LGKM0();                       // {A0,B0}(cb) reads retired (drained under prev MFMA)
        STAGE_B(cb ^ 1, 0, t1);
        MFMAQ(0, 0, bf0v);
        LOAD_B(cb, 1, bf1v);           // read-ahead for ph2
        // ---- phase 2: Q(0,1) ----
        BAR();
        LGKM0();
        STAGE_A(cb, 0, t2);            // safe: A0 reads retired by all waves at ph1 lgkm
        MFMAQ(0, 1, bf1v);
        LOAD_A(cb, 1);                 // read-ahead for ph3
        // ---- phase 3: Q(1,0) ----
        BAR();
        LGKM0();
        STAGE_B(cb, 1, t2);            // safe: B1 reads retired at ph2 lgkm
        MFMAQ(1, 0, bf0v);
        // ---- phase 4: Q(1,1) ----
        asm volatile("s_waitcnt vmcnt(4)" ::: "memory");  // retires through B0(t+1)
        BAR();
        STAGE_A(cb, 1, t2);            // safe: A1 reads retired at ph3 lgkm, after bar4
        MFMAQ(1, 1, bf1v);
        LOAD_A(cb ^ 1, 0);             // read-ahead for next tile's ph1
        LOAD_B(cb ^ 1, 0, bf0v);       // (tile t+1 fully landed via vmcnt(4)+bar)
    }
    asm volatile("s_waitcnt vmcnt(0) lgkmcnt(0)" ::: "memory");  // drain tail

    // epilogue: C row = tileM + (i>>2)*128 + wave_m*64 + (i&3)*16 + quad*4 + r
    //           C col = tileN + (j>>1)*128 + wave_n*32 + (j&1)*16 + r16
#pragma unroll
    for (int i = 0; i < 8; ++i) {
        const int row0 = tileM + (i >> 2) * 128 + wave_m * 64 + (i & 3) * 16 + quad * 4;
#pragma unroll
        for (int j = 0; j < 4; ++j) {
            const int col = tileN + (j >> 1) * 128 + wave_n * 32 + (j & 1) * 16 + r16;
            const float bv = bias[col];
#pragma unroll
            for (int r = 0; r < 4; ++r) {
                float v = acc[i][j][r] + bv;
                if (EPI == 0) {
                    ((unsigned short*)Cp)[(size_t)(row0 + r) * N + col] = f2bf(v);
                } else {
                    ((float*)Cp)[(size_t)(row0 + r) * N + col] = fmaxf(v, 0.0f);
                }
            }
        }
    }
#undef GLL
#undef STAGE_A
#undef STAGE_B
#undef LOAD_A
#undef LOAD_B
#undef MFMAQ
#undef BAR
#undef LGKM0
}

// ---------------- scan phase A: per-chunk local end values (4 ch/thread) ----------------
// u: bf16 [B*L, 2D] (re/im interleaved per channel). Eend: [SS][B*D] float2.
// 16 B/lane uint4 loads (coalescing sweet spot); 2x float4 stores.
__global__ __launch_bounds__(256)
void scanA(const unsigned short* __restrict__ u,
           const float* __restrict__ plog,
           float2* __restrict__ Eend) {
    const int d0 = (blockIdx.x * 256 + threadIdx.x) * 4;
    const int c = blockIdx.y, b = blockIdx.z;
    float lr[4], li[4], zr[4], zi[4];
#pragma unroll
    for (int j = 0; j < 4; ++j) {
        const float v  = expf(plog[d0 + j]);
        const float th = expf(plog[DD + d0 + j]);
        const float a  = expf(-v);
        lr[j] = a * cosf(th); li[j] = a * sinf(th);
        zr[j] = 0.f; zi[j] = 0.f;
    }
    const unsigned short* up = u + (size_t)(b * LL + c * TT) * (2 * DD) + 2 * d0;
#pragma unroll 8
    for (int tl = 0; tl < TT; ++tl) {
        uint4 pr = *(const uint4*)up;
        unsigned int w[4] = {pr.x, pr.y, pr.z, pr.w};
#pragma unroll
        for (int j = 0; j < 4; ++j) {
            float xr = bf2f((unsigned short)(w[j] & 0xffffu));
            float xi = bf2f((unsigned short)(w[j] >> 16));
            float t = lr[j] * zr[j] - li[j] * zi[j] + xr;
            zi[j] = lr[j] * zi[j] + li[j] * zr[j] + xi;
            zr[j] = t;
        }
        up += 2 * DD;
    }
    float4* ep = (float4*)&Eend[(size_t)c * (BB * DD) + b * DD + d0];
    ep[0] = make_float4(zr[0], zi[0], zr[1], zi[1]);
    ep[1] = make_float4(zr[2], zi[2], zr[3], zi[3]);
}

// ---------------- scan phase B: in-place exclusive carry prefix over chunks ----
// E[c][b][d] : on entry = chunk-local end values; on exit = carry INTO chunk c.
__global__ __launch_bounds__(256)
void scanB(const float* __restrict__ plog, float2* __restrict__ E) {
    const int i = blockIdx.x * 256 + threadIdx.x;   // i = b*DD + d
    const int d = i & (DD - 1);
    const float v  = expf(plog[d]);
    const float th = expf(plog[DD + d]);
    const float aT = expf(-(float)TT * v);
    const float Lr = aT * cosf((float)TT * th), Li = aT * sinf((float)TT * th);
    float yr = 0.f, yi = 0.f;
    float2* p = E + i;
#pragma unroll 8
    for (int c = 0; c < SS; ++c) {
        float2 e = *p;
        *p = make_float2(yr, yi);      // exclusive prefix (safe in-place: 1 thread per [*][i])
        float t = Lr * yr - Li * yi + e.x;
        yi = Lr * yi + Li * yr + e.y;
        yr = t;
        p += BB * DD;
    }
}

// ---------------- scan phase C: local scan from carry + gamma (4 ch/thread) ----
// xr layout: [B*L, 2D] with col d = gamma*Re(y), col DD+d = gamma*Im(y).
// 16 B/lane uint4 loads; 8 B ushort4 stores (Re-pack, Im-pack of 4 channels).
__global__ __launch_bounds__(256)
void scanC(const unsigned short* __restrict__ u,
           const float* __restrict__ plog,
           const float2* __restrict__ Carry,
           unsigned short* __restrict__ xr) {
    const int d0 = (blockIdx.x * 256 + threadIdx.x) * 4;
    const int c = blockIdx.y, b = blockIdx.z;
    float lr[4], li[4], g[4], yr[4], yi[4];
#pragma unroll
    for (int j = 0; j < 4; ++j) {
        const float v  = expf(plog[d0 + j]);
        const float th = expf(plog[DD + d0 + j]);
        g[j] = expf(plog[2 * DD + d0 + j]);
        const float a = expf(-v);
        lr[j] = a * cosf(th); li[j] = a * sinf(th);
    }
    {
        const float4* cp = (const float4*)&Carry[(size_t)c * (BB * DD) + b * DD + d0];
        float4 c0 = cp[0], c1 = cp[1];
        yr[0] = c0.x; yi[0] = c0.y; yr[1] = c0.z; yi[1] = c0.w;
        yr[2] = c1.x; yi[2] = c1.y; yr[3] = c1.z; yi[3] = c1.w;
    }
    const unsigned short* up = u + (size_t)(b * LL + c * TT) * (2 * DD) + 2 * d0;
    unsigned short* xp = xr + (size_t)(b * LL + c * TT) * (2 * DD) + d0;
#pragma unroll 8
    for (int tl = 0; tl < TT; ++tl) {
        uint4 pr = *(const uint4*)up;
        unsigned int w[4] = {pr.x, pr.y, pr.z, pr.w};
        ushort4 ore, oim;
        unsigned short re[4], im[4];
#pragma unroll
        for (int j = 0; j < 4; ++j) {
            float xrv = bf2f((unsigned short)(w[j] & 0xffffu));
            float xiv = bf2f((unsigned short)(w[j] >> 16));
            float t = lr[j] * yr[j] - li[j] * yi[j] + xrv;
            yi[j] = lr[j] * yi[j] + li[j] * yr[j] + xiv;
            yr[j] = t;
            re[j] = f2bf(g[j] * yr[j]);
            im[j] = f2bf(g[j] * yi[j]);
        }
        ore.x = re[0]; ore.y = re[1]; ore.z = re[2]; ore.w = re[3];
        oim.x = im[0]; oim.y = im[1]; oim.z = im[2]; oim.w = im[3];
        *(ushort4*)&xp[0]  = ore;
        *(ushort4*)&xp[DD] = oim;
        up += 2 * DD;
        xp += 2 * DD;
    }
}

extern "C" void kernel_launch(void* const* d_in, const int* in_sizes, int n_in,
                              void* d_out, int out_size, void* d_ws, size_t ws_size,
                              hipStream_t stream) {
    const float* inputs = (const float*)d_in[0];   // B*L*D = 16777216
    const float* Wi     = (const float*)d_in[1];   // 2D*D  = 2097152
    const float* bi     = (const float*)d_in[2];   // 2D
    const float* Wo     = (const float*)d_in[3];   // D*2D  = 2097152
    const float* bo     = (const float*)d_in[4];   // D
    const float* plog   = (const float*)d_in[5];   // 3*D
    float* out = (float*)d_out;

    const size_t M = (size_t)BB * LL;              // 16384
    unsigned short* u_bf  = (unsigned short*)d_ws;             // M*2D bf16  (64 MB)
    unsigned short* xr_bf = u_bf  + M * 2 * DD;                // M*2D bf16  (64 MB)
    unsigned short* in_bf = xr_bf + M * 2 * DD;                // M*D  bf16  (32 MB)
    unsigned short* Wi_bf = in_bf + M * DD;                    // 2D*D bf16  (4 MB)
    unsigned short* Wo_bf = Wi_bf + (size_t)2 * DD * DD;       // D*2D bf16  (4 MB)
    // Eend/Carry (SS*B*D float2 = 4 MB) aliases in_bf: in_bf is dead after
    // GEMM1 completes, and scanA (the first Eend writer) runs after GEMM1.
    float2* Eend = (float2*)in_bf;

    // merged bf16 casts (inputs + Wi + Wo) in one dispatch
    {
        int total4 = NIN4 + 2 * NW4;
        cast_all_kernel<<<total4 / 256, 256, 0, stream>>>(
            (const float4*)inputs, (ushort4*)in_bf,
            (const float4*)Wi,     (ushort4*)Wi_bf,
            (const float4*)Wo,     (ushort4*)Wo_bf);
    }

    // GEMM1: u[M, 2D] = in_bf[M, D] @ Wi^T + bi   (bf16 out), N=2048 -> NT=8
    gemm256<DD, 8, 0><<<(M / 256) * 8, 512, 0, stream>>>(
        in_bf, Wi_bf, bi, (void*)u_bf);

    // scan: per-chunk local ends -> carry prefix (in place) -> fix-up + gamma
    scanA<<<dim3(DD / 1024, SS, BB), 256, 0, stream>>>(u_bf, plog, Eend);
    scanB<<<(BB * DD) / 256, 256, 0, stream>>>(plog, Eend);
    scanC<<<dim3(DD / 1024, SS, BB), 256, 0, stream>>>(u_bf, plog, Eend, xr_bf);

    // GEMM2: out[M, D] = relu(xr[M, 2D] @ Wo^T + bo)  (f32 out), N=1024 -> NT=4
    gemm256<2 * DD, 4, 1><<<(M / 256) * 4, 512, 0, stream>>>(
        xr_bf, Wo_bf, bo, (void*)out);
}

// Round 6
// 301.841 us; speedup vs baseline: 1.0169x; 1.0169x over previous
//
#include <hip/hip_runtime.h>

// Problem constants (B, L_IN, D) = (4, 4096, 1024)
#define BB 4
#define LL 4096
#define DD 1024
#define SS 128  // number of chunks in the scan
#define TT 32   // chunk length (SS*TT == LL)

typedef __attribute__((ext_vector_type(4))) float  floatx4;
typedef __attribute__((ext_vector_type(8))) short  shortx8;
typedef __attribute__((ext_vector_type(8))) unsigned short ushortx8;

static __device__ __forceinline__ unsigned short f2bf(float f) {
    unsigned int u = __float_as_uint(f);
    u += 0x7fffu + ((u >> 16) & 1u);           // round-to-nearest-even
    return (unsigned short)(u >> 16);
}
static __device__ __forceinline__ float bf2f(unsigned short h) {
    return __uint_as_float(((unsigned int)h) << 16);
}

// ---------------- merged f32 -> bf16 cast (inputs + Wi + Wo-interleaved) ----
// Wo is cast WITH K-column interleave: WoP[n][2d] = Wo[n][d] (re),
// WoP[n][2d+1] = Wo[n][DD+d] (im). xr is produced in the same interleaved
// K-layout by scanC, so GEMM2 (out = xr @ Wo^T) is unchanged semantically.
#define NIN4 (BB * LL * DD / 4)          // 4194304
#define NWI4 (2 * DD * DD / 4)           // 524288
#define NWO8 (DD * DD / 4)               // 262144 (8 outputs/thread)
__global__ void cast_all_kernel(const float4* __restrict__ s_in, ushort4* __restrict__ d_inb,
                                const float4* __restrict__ s_wi, ushort4* __restrict__ d_wib,
                                const float* __restrict__ s_wo, unsigned short* __restrict__ d_wob) {
    int i = blockIdx.x * blockDim.x + threadIdx.x;
    if (i < NIN4 + NWI4) {
        const float4* s; ushort4* d; int j;
        if (i < NIN4) { s = s_in; d = d_inb; j = i; }
        else          { s = s_wi; d = d_wib; j = i - NIN4; }
        float4 v = s[j];
        ushort4 o;
        o.x = f2bf(v.x); o.y = f2bf(v.y); o.z = f2bf(v.z); o.w = f2bf(v.w);
        d[j] = o;
    } else {
        int j = i - NIN4 - NWI4;               // j < NWO8
        int n  = j >> 8;                       // row (DD/4 = 256 quads per row)
        int d0 = (j & 255) * 4;
        const float* rowp = s_wo + (size_t)n * (2 * DD);
        float4 re = *(const float4*)(rowp + d0);
        float4 im = *(const float4*)(rowp + DD + d0);
        ushortx8 o;
        o[0] = f2bf(re.x); o[1] = f2bf(im.x);
        o[2] = f2bf(re.y); o[3] = f2bf(im.y);
        o[4] = f2bf(re.z); o[5] = f2bf(im.z);
        o[6] = f2bf(re.w); o[7] = f2bf(im.w);
        *(ushortx8*)(d_wob + (size_t)n * (2 * DD) + 2 * d0) = o;
    }
}

// ---------------- bf16 GEMM: C[M,N] = A[M,K] * B[N,K]^T + bias ----------------
// 256x256 tile, BK=64, 512 threads = 8 waves (2M x 4N), per-wave 128x64 output.
// READ-AHEAD 4-phase schedule (best measured r2 variant): each phase issues the
// NEXT phase's ds_reads AFTER its MFMA cluster, so read drain hides under MFMA
// + barrier; one raw s_barrier per phase; counted vmcnt(4) once per K-tile.
//
// Hazard proof (semantic, no timing assumptions). R(p) = reads pending at
// phase p top (issued end of p-1); S(p) = region staged in phase p.
//   R(ph1)={A0,B0}(cb)  R(ph2)={B1(cb)}  R(ph3)={A1(cb)}  R(ph4)={}
//   S(ph1)=B0(cb^1,t+1) S(ph2)=A0(cb,t+2) S(ph3)=B1(cb,t+2) S(ph4)=A1(cb,t+2)
// 1) S(p) ∩ R(p) = ∅ and S(p) ∩ R(p+1) = ∅ for all p.
// 2) Every S(p) overwriting a previously-read region is issued after a barrier
//    whose arrival implies all waves retired those reads via lgkmcnt(0).
// 3) vmcnt(4) before bar4 retires everything through S(ph1)=B0(t+1);
//    end-of-ph4 reads {A0,B0}(cb^1,t+1) are issued after bar4.
//
// LDS chunk swizzle (verified, 0 bank conflicts): within each 128-row
// half-tile, chunk q holds row=q>>3, k8=(q&7)^(row&7); reads XOR with r16&7.
template<int K, int NT, int EPI>
__global__ __launch_bounds__(512, 2)
void gemm256(const unsigned short* __restrict__ A,
             const unsigned short* __restrict__ B,
             const float* __restrict__ bias,
             void* __restrict__ Cp) {
    constexpr int N   = NT * 256;
    constexpr int NKT = K / 64;            // 16 or 32 here
    __shared__ __align__(16) short As[2][256 * 64];   // 64 KB
    __shared__ __align__(16) short Bs[2][256 * 64];   // 64 KB

    const int tid = threadIdx.x;
    const int blk = blockIdx.x;
    const int xcd = blk & 7;
    const int i2  = blk >> 3;
    const int tileM = ((i2 / NT) * 8 + xcd) * 256;
    const int tileN = (i2 % NT) * 256;

    const int lane   = tid & 63;
    const int wave   = tid >> 6;
    const int wave_m = wave >> 2;          // 0..1
    const int wave_n = wave & 3;           // 0..3
    const int r16    = lane & 15;
    const int quad   = lane >> 4;
    const int slotx  = r16 & 7;
    const int wmRow  = wave_m * 64 + r16;
    const int wnRow  = wave_n * 32 + r16;

    const int srow = tid >> 3;                         // 0..63
    const int scol = ((tid & 7) ^ (srow & 7)) * 8;     // pre-swizzled k offset (shorts)
    const int ldsChunkBase = (tid & ~63) * 8;          // shorts
    const size_t aOff = (size_t)(tileM + srow) * K + scol;
    const size_t bOff = (size_t)(tileN + srow) * K + scol;

    floatx4 acc[8][4] = {};
    shortx8 af[4][2], bf0v[2][2], bf1v[2][2];

#define GLL(SRC, DST) __builtin_amdgcn_global_load_lds( \
        (const __attribute__((address_space(1))) void*)(SRC), \
        (__attribute__((address_space(3))) void*)(DST), 16, 0, 0)
#define STAGE_A(BUF, H, KT) do { \
    GLL(A + aOff + (size_t)((H) * 128) * K + (KT) * 64,      &As[BUF][(H) * 8192 + ldsChunkBase]); \
    GLL(A + aOff + (size_t)((H) * 128 + 64) * K + (KT) * 64, &As[BUF][(H) * 8192 + 4096 + ldsChunkBase]); \
} while (0)
#define STAGE_B(BUF, H, KT) do { \
    GLL(B + bOff + (size_t)((H) * 128) * K + (KT) * 64,      &Bs[BUF][(H) * 8192 + ldsChunkBase]); \
    GLL(B + bOff + (size_t)((H) * 128 + 64) * K + (KT) * 64, &Bs[BUF][(H) * 8192 + 4096 + ldsChunkBase]); \
} while (0)
#define LOAD_A(BUF, MH) do { \
    _Pragma("unroll") for (int il = 0; il < 4; ++il) \
    _Pragma("unroll") for (int kk = 0; kk < 2; ++kk) \
        af[il][kk] = *(const shortx8*)&As[BUF][((MH) * 128 + wmRow + il * 16) * 64 + ((kk * 4 + quad) ^ slotx) * 8]; \
} while (0)
#define LOAD_B(BUF, NH, DST) do { \
    _Pragma("unroll") for (int jl = 0; jl < 2; ++jl) \
    _Pragma("unroll") for (int kk = 0; kk < 2; ++kk) \
        DST[jl][kk] = *(const shortx8*)&Bs[BUF][((NH) * 128 + wnRow + jl * 16) * 64 + ((kk * 4 + quad) ^ slotx) * 8]; \
} while (0)
#define MFMAQ(MH, NH, BF) do { \
    __builtin_amdgcn_s_setprio(1); \
    _Pragma("unroll") for (int kk = 0; kk < 2; ++kk) \
    _Pragma("unroll") for (int il = 0; il < 4; ++il) \
    _Pragma("unroll") for (int jl = 0; jl < 2; ++jl) \
        acc[(MH) * 4 + il][(NH) * 2 + jl] = __builtin_amdgcn_mfma_f32_16x16x32_bf16( \
            af[il][kk], BF[jl][kk], acc[(MH) * 4 + il][(NH) * 2 + jl], 0, 0, 0); \
    __builtin_amdgcn_s_setprio(0); \
} while (0)
#define BAR()  __builtin_amdgcn_s_barrier()
#define LGKM0() asm volatile("s_waitcnt lgkmcnt(0)" ::: "memory")

    // prologue: tile0 (A0,B0,B1,A1) + A0(1),B1(1),A1(1) = 14 GLLs
    STAGE_A(0, 0, 0);
    STAGE_B(0, 0, 0);
    STAGE_B(0, 1, 0);
    STAGE_A(0, 1, 0);
    STAGE_A(1, 0, 1);
    STAGE_B(1, 1, 1);
    STAGE_A(1, 1, 1);
    asm volatile("s_waitcnt vmcnt(6)" ::: "memory");   // tile0 landed; 6 in flight
    BAR();
    // pre-issue ph1(t=0) operands
    LOAD_A(0, 0);
    LOAD_B(0, 0, bf0v);

#pragma unroll 2
    for (int t = 0; t < NKT; ++t) {
        const int cb = t & 1;
        const int t1 = (t + 1 < NKT) ? t + 1 : NKT - 1;   // clamped tail: keeps
        const int t2 = (t + 2 < NKT) ? t + 2 : NKT - 1;   // vmcnt counts uniform
        // ---- phase 1: Q(0,0) ----
        BAR();
        LGKM0();                       // {A0,B0}(cb) reads retired (drained under prev MFMA)
        STAGE_B(cb ^ 1, 0, t1);
        MFMAQ(0, 0, bf0v);
        LOAD_B(cb, 1, bf1v);           // read-ahead for ph2
        // ---- phase 2: Q(0,1) ----
        BAR();
        LGKM0();
        STAGE_A(cb, 0, t2);            // safe: A0 reads retired by all waves at ph1 lgkm
        MFMAQ(0, 1, bf1v);
        LOAD_A(cb, 1);                 // read-ahead for ph3
        // ---- phase 3: Q(1,0) ----
        BAR();
        LGKM0();
        STAGE_B(cb, 1, t2);            // safe: B1 reads retired at ph2 lgkm
        MFMAQ(1, 0, bf0v);
        // ---- phase 4: Q(1,1) ----
        asm volatile("s_waitcnt vmcnt(4)" ::: "memory");  // retires through B0(t+1)
        BAR();
        STAGE_A(cb, 1, t2);            // safe: A1 reads retired at ph3 lgkm, after bar4
        MFMAQ(1, 1, bf1v);
        LOAD_A(cb ^ 1, 0);             // read-ahead for next tile's ph1
        LOAD_B(cb ^ 1, 0, bf0v);       // (tile t+1 fully landed via vmcnt(4)+bar)
    }
    asm volatile("s_waitcnt vmcnt(0) lgkmcnt(0)" ::: "memory");  // drain tail

    // epilogue: C row = tileM + (i>>2)*128 + wave_m*64 + (i&3)*16 + quad*4 + r
    //           C col = tileN + (j>>1)*128 + wave_n*32 + (j&1)*16 + r16
#pragma unroll
    for (int i = 0; i < 8; ++i) {
        const int row0 = tileM + (i >> 2) * 128 + wave_m * 64 + (i & 3) * 16 + quad * 4;
#pragma unroll
        for (int j = 0; j < 4; ++j) {
            const int col = tileN + (j >> 1) * 128 + wave_n * 32 + (j & 1) * 16 + r16;
            const float bv = bias[col];
#pragma unroll
            for (int r = 0; r < 4; ++r) {
                float v = acc[i][j][r] + bv;
                if (EPI == 0) {
                    ((unsigned short*)Cp)[(size_t)(row0 + r) * N + col] = f2bf(v);
                } else {
                    ((float*)Cp)[(size_t)(row0 + r) * N + col] = fmaxf(v, 0.0f);
                }
            }
        }
    }
#undef GLL
#undef STAGE_A
#undef STAGE_B
#undef LOAD_A
#undef LOAD_B
#undef MFMAQ
#undef BAR
#undef LGKM0
}

// ---------------- scan phase A: per-chunk local end values (1 ch/thread) ----------------
// u: bf16 [B*L, 2D] (re/im interleaved per channel). Eend: [SS][B*D] float2.
// Grid (DD/256, SS, BB) = (4,128,4): 8192 waves = 8/SIMD for latency hiding.
__global__ __launch_bounds__(256)
void scanA(const unsigned short* __restrict__ u,
           const float* __restrict__ plog,
           float2* __restrict__ Eend) {
    const int d = blockIdx.x * 256 + threadIdx.x;
    const int c = blockIdx.y, b = blockIdx.z;
    const float v  = expf(plog[d]);
    const float th = expf(plog[DD + d]);
    const float a  = expf(-v);
    const float lr = a * cosf(th), li = a * sinf(th);
    float zr = 0.f, zi = 0.f;
    const unsigned short* up = u + (size_t)(b * LL + c * TT) * (2 * DD) + 2 * d;
#pragma unroll 8
    for (int tl = 0; tl < TT; ++tl) {
        unsigned int pr = *(const unsigned int*)up;
        float xr = bf2f((unsigned short)(pr & 0xffffu));
        float xi = bf2f((unsigned short)(pr >> 16));
        float t = lr * zr - li * zi + xr;
        zi = lr * zi + li * zr + xi;
        zr = t;
        up += 2 * DD;
    }
    Eend[(size_t)c * (BB * DD) + b * DD + d] = make_float2(zr, zi);
}

// ---------------- scan phase B: in-place exclusive carry prefix over chunks ----
// E[c][b][d] : on entry = chunk-local end values; on exit = carry INTO chunk c.
// 64 blocks x 64 threads: spread across 64 CUs (more HBM channels engaged);
// unroll 16 keeps 16 independent loads in flight per thread.
__global__ __launch_bounds__(64)
void scanB(const float* __restrict__ plog, float2* __restrict__ E) {
    const int i = blockIdx.x * 64 + threadIdx.x;   // i = b*DD + d
    const int d = i & (DD - 1);
    const float v  = expf(plog[d]);
    const float th = expf(plog[DD + d]);
    const float aT = expf(-(float)TT * v);
    const float Lr = aT * cosf((float)TT * th), Li = aT * sinf((float)TT * th);
    float yr = 0.f, yi = 0.f;
    float2* p = E + i;
#pragma unroll 16
    for (int c = 0; c < SS; ++c) {
        float2 e = *p;
        *p = make_float2(yr, yi);      // exclusive prefix (safe in-place: 1 thread per [*][i])
        float t = Lr * yr - Li * yi + e.x;
        yi = Lr * yi + Li * yr + e.y;
        yr = t;
        p += BB * DD;
    }
}

// ---------------- scan phase C: local scan from carry + gamma (1 ch/thread) ----
// xr K-layout is INTERLEAVED: xr[m][2d] = gamma*Re(y_d), xr[m][2d+1] =
// gamma*Im(y_d) — matches WoP's interleaved columns (cast kernel), so GEMM2's
// dot products are a pure K-permutation of the reference. One aligned 4B uint
// store per step (wave = 256B contiguous) instead of two 2B scalar stores.
__global__ __launch_bounds__(256)
void scanC(const unsigned short* __restrict__ u,
           const float* __restrict__ plog,
           const float2* __restrict__ Carry,
           unsigned short* __restrict__ xr) {
    const int d = blockIdx.x * 256 + threadIdx.x;
    const int c = blockIdx.y, b = blockIdx.z;
    const float v  = expf(plog[d]);
    const float th = expf(plog[DD + d]);
    const float g  = expf(plog[2 * DD + d]);
    const float a  = expf(-v);
    const float lr = a * cosf(th), li = a * sinf(th);
    const float2 cy = Carry[(size_t)c * (BB * DD) + b * DD + d];
    float yr = cy.x, yi = cy.y;
    const unsigned short* up = u + (size_t)(b * LL + c * TT) * (2 * DD) + 2 * d;
    unsigned short* xp = xr + (size_t)(b * LL + c * TT) * (2 * DD) + 2 * d;
#pragma unroll 8
    for (int tl = 0; tl < TT; ++tl) {
        unsigned int pr = *(const unsigned int*)up;
        float xrv = bf2f((unsigned short)(pr & 0xffffu));
        float xiv = bf2f((unsigned short)(pr >> 16));
        float t = lr * yr - li * yi + xrv;
        yi = lr * yi + li * yr + xiv;
        yr = t;
        *(unsigned int*)xp = (unsigned int)f2bf(g * yr) |
                             ((unsigned int)f2bf(g * yi) << 16);
        up += 2 * DD;
        xp += 2 * DD;
    }
}

extern "C" void kernel_launch(void* const* d_in, const int* in_sizes, int n_in,
                              void* d_out, int out_size, void* d_ws, size_t ws_size,
                              hipStream_t stream) {
    const float* inputs = (const float*)d_in[0];   // B*L*D = 16777216
    const float* Wi     = (const float*)d_in[1];   // 2D*D  = 2097152
    const float* bi     = (const float*)d_in[2];   // 2D
    const float* Wo     = (const float*)d_in[3];   // D*2D  = 2097152
    const float* bo     = (const float*)d_in[4];   // D
    const float* plog   = (const float*)d_in[5];   // 3*D
    float* out = (float*)d_out;

    const size_t M = (size_t)BB * LL;              // 16384
    unsigned short* u_bf  = (unsigned short*)d_ws;             // M*2D bf16  (64 MB)
    unsigned short* xr_bf = u_bf  + M * 2 * DD;                // M*2D bf16  (64 MB)
    unsigned short* in_bf = xr_bf + M * 2 * DD;                // M*D  bf16  (32 MB)
    unsigned short* Wi_bf = in_bf + M * DD;                    // 2D*D bf16  (4 MB)
    unsigned short* Wo_bf = Wi_bf + (size_t)2 * DD * DD;       // D*2D bf16  (4 MB)
    // Eend/Carry (SS*B*D float2 = 4 MB) aliases in_bf: in_bf is dead after
    // GEMM1 completes, and scanA (the first Eend writer) runs after GEMM1.
    float2* Eend = (float2*)in_bf;

    // merged bf16 casts (inputs + Wi + Wo-interleaved) in one dispatch
    {
        int total = NIN4 + NWI4 + NWO8;            // 4980736, divisible by 256
        cast_all_kernel<<<total / 256, 256, 0, stream>>>(
            (const float4*)inputs, (ushort4*)in_bf,
            (const float4*)Wi,     (ushort4*)Wi_bf,
            Wo,                    Wo_bf);
    }

    // GEMM1: u[M, 2D] = in_bf[M, D] @ Wi^T + bi   (bf16 out), N=2048 -> NT=8
    gemm256<DD, 8, 0><<<(M / 256) * 8, 512, 0, stream>>>(
        in_bf, Wi_bf, bi, (void*)u_bf);

    // scan: per-chunk local ends -> carry prefix (in place) -> fix-up + gamma
    scanA<<<dim3(DD / 256, SS, BB), 256, 0, stream>>>(u_bf, plog, Eend);
    scanB<<<(BB * DD) / 64, 64, 0, stream>>>(plog, Eend);
    scanC<<<dim3(DD / 256, SS, BB), 256, 0, stream>>>(u_bf, plog, Eend, xr_bf);

    // GEMM2: out[M, D] = relu(xr[M, 2D] @ WoP^T + bo)  (f32 out), N=1024 -> NT=4
    gemm256<2 * DD, 4, 1><<<(M / 256) * 4, 512, 0, stream>>>(
        xr_bf, Wo_bf, bo, (void*)out);
}

// Round 7
// 300.694 us; speedup vs baseline: 1.0208x; 1.0038x over previous
//
#include <hip/hip_runtime.h>
#include <hip/hip_cooperative_groups.h>

// Problem constants (B, L_IN, D) = (4, 4096, 1024)
#define BB 4
#define LL 4096
#define DD 1024
#define SS 128  // number of chunks in the scan
#define TT 32   // chunk length (SS*TT == LL)

typedef __attribute__((ext_vector_type(4))) float  floatx4;
typedef __attribute__((ext_vector_type(8))) short  shortx8;
typedef __attribute__((ext_vector_type(8))) unsigned short ushortx8;

static __device__ __forceinline__ unsigned short f2bf(float f) {
    unsigned int u = __float_as_uint(f);
    u += 0x7fffu + ((u >> 16) & 1u);           // round-to-nearest-even
    return (unsigned short)(u >> 16);
}
static __device__ __forceinline__ float bf2f(unsigned short h) {
    return __uint_as_float(((unsigned int)h) << 16);
}

// ---------------- merged f32 -> bf16 cast (inputs + Wi + Wo-interleaved) ----
// Wo is cast WITH K-column interleave: WoP[n][2d] = Wo[n][d] (re),
// WoP[n][2d+1] = Wo[n][DD+d] (im). xr is produced in the same interleaved
// K-layout by the scan, so GEMM2 (out = xr @ Wo^T) is unchanged semantically.
#define NIN4 (BB * LL * DD / 4)          // 4194304
#define NWI4 (2 * DD * DD / 4)           // 524288
#define NWO8 (DD * DD / 4)               // 262144 (8 outputs/thread)
__global__ void cast_all_kernel(const float4* __restrict__ s_in, ushort4* __restrict__ d_inb,
                                const float4* __restrict__ s_wi, ushort4* __restrict__ d_wib,
                                const float* __restrict__ s_wo, unsigned short* __restrict__ d_wob) {
    int i = blockIdx.x * blockDim.x + threadIdx.x;
    if (i < NIN4 + NWI4) {
        const float4* s; ushort4* d; int j;
        if (i < NIN4) { s = s_in; d = d_inb; j = i; }
        else          { s = s_wi; d = d_wib; j = i - NIN4; }
        float4 v = s[j];
        ushort4 o;
        o.x = f2bf(v.x); o.y = f2bf(v.y); o.z = f2bf(v.z); o.w = f2bf(v.w);
        d[j] = o;
    } else {
        int j = i - NIN4 - NWI4;               // j < NWO8
        int n  = j >> 8;                       // row (DD/4 = 256 quads per row)
        int d0 = (j & 255) * 4;
        const float* rowp = s_wo + (size_t)n * (2 * DD);
        float4 re = *(const float4*)(rowp + d0);
        float4 im = *(const float4*)(rowp + DD + d0);
        ushortx8 o;
        o[0] = f2bf(re.x); o[1] = f2bf(im.x);
        o[2] = f2bf(re.y); o[3] = f2bf(im.y);
        o[4] = f2bf(re.z); o[5] = f2bf(im.z);
        o[6] = f2bf(re.w); o[7] = f2bf(im.w);
        *(ushortx8*)(d_wob + (size_t)n * (2 * DD) + 2 * d0) = o;
    }
}

// ---------------- bf16 GEMM: C[M,N] = A[M,K] * B[N,K]^T + bias ----------------
// 256x256 tile, BK=64, 512 threads = 8 waves (2M x 4N), per-wave 128x64 output.
// READ-AHEAD 4-phase schedule (best measured r2 variant): each phase issues the
// NEXT phase's ds_reads AFTER its MFMA cluster, so read drain hides under MFMA
// + barrier; one raw s_barrier per phase; counted vmcnt(4) once per K-tile.
//
// Hazard proof (semantic, no timing assumptions). R(p) = reads pending at
// phase p top (issued end of p-1); S(p) = region staged in phase p.
//   R(ph1)={A0,B0}(cb)  R(ph2)={B1(cb)}  R(ph3)={A1(cb)}  R(ph4)={}
//   S(ph1)=B0(cb^1,t+1) S(ph2)=A0(cb,t+2) S(ph3)=B1(cb,t+2) S(ph4)=A1(cb,t+2)
// 1) S(p) ∩ R(p) = ∅ and S(p) ∩ R(p+1) = ∅ for all p.
// 2) Every S(p) overwriting a previously-read region is issued after a barrier
//    whose arrival implies all waves retired those reads via lgkmcnt(0).
// 3) vmcnt(4) before bar4 retires everything through S(ph1)=B0(t+1);
//    end-of-ph4 reads {A0,B0}(cb^1,t+1) are issued after bar4.
//
// LDS chunk swizzle (verified, 0 bank conflicts): within each 128-row
// half-tile, chunk q holds row=q>>3, k8=(q&7)^(row&7); reads XOR with r16&7.
template<int K, int NT, int EPI>
__global__ __launch_bounds__(512, 2)
void gemm256(const unsigned short* __restrict__ A,
             const unsigned short* __restrict__ B,
             const float* __restrict__ bias,
             void* __restrict__ Cp) {
    constexpr int N   = NT * 256;
    constexpr int NKT = K / 64;            // 16 or 32 here
    __shared__ __align__(16) short As[2][256 * 64];   // 64 KB
    __shared__ __align__(16) short Bs[2][256 * 64];   // 64 KB

    const int tid = threadIdx.x;
    const int blk = blockIdx.x;
    const int xcd = blk & 7;
    const int i2  = blk >> 3;
    const int tileM = ((i2 / NT) * 8 + xcd) * 256;
    const int tileN = (i2 % NT) * 256;

    const int lane   = tid & 63;
    const int wave   = tid >> 6;
    const int wave_m = wave >> 2;          // 0..1
    const int wave_n = wave & 3;           // 0..3
    const int r16    = lane & 15;
    const int quad   = lane >> 4;
    const int slotx  = r16 & 7;
    const int wmRow  = wave_m * 64 + r16;
    const int wnRow  = wave_n * 32 + r16;

    const int srow = tid >> 3;                         // 0..63
    const int scol = ((tid & 7) ^ (srow & 7)) * 8;     // pre-swizzled k offset (shorts)
    const int ldsChunkBase = (tid & ~63) * 8;          // shorts
    const size_t aOff = (size_t)(tileM + srow) * K + scol;
    const size_t bOff = (size_t)(tileN + srow) * K + scol;

    floatx4 acc[8][4] = {};
    shortx8 af[4][2], bf0v[2][2], bf1v[2][2];

#define GLL(SRC, DST) __builtin_amdgcn_global_load_lds( \
        (const __attribute__((address_space(1))) void*)(SRC), \
        (__attribute__((address_space(3))) void*)(DST), 16, 0, 0)
#define STAGE_A(BUF, H, KT) do { \
    GLL(A + aOff + (size_t)((H) * 128) * K + (KT) * 64,      &As[BUF][(H) * 8192 + ldsChunkBase]); \
    GLL(A + aOff + (size_t)((H) * 128 + 64) * K + (KT) * 64, &As[BUF][(H) * 8192 + 4096 + ldsChunkBase]); \
} while (0)
#define STAGE_B(BUF, H, KT) do { \
    GLL(B + bOff + (size_t)((H) * 128) * K + (KT) * 64,      &Bs[BUF][(H) * 8192 + ldsChunkBase]); \
    GLL(B + bOff + (size_t)((H) * 128 + 64) * K + (KT) * 64, &Bs[BUF][(H) * 8192 + 4096 + ldsChunkBase]); \
} while (0)
#define LOAD_A(BUF, MH) do { \
    _Pragma("unroll") for (int il = 0; il < 4; ++il) \
    _Pragma("unroll") for (int kk = 0; kk < 2; ++kk) \
        af[il][kk] = *(const shortx8*)&As[BUF][((MH) * 128 + wmRow + il * 16) * 64 + ((kk * 4 + quad) ^ slotx) * 8]; \
} while (0)
#define LOAD_B(BUF, NH, DST) do { \
    _Pragma("unroll") for (int jl = 0; jl < 2; ++jl) \
    _Pragma("unroll") for (int kk = 0; kk < 2; ++kk) \
        DST[jl][kk] = *(const shortx8*)&Bs[BUF][((NH) * 128 + wnRow + jl * 16) * 64 + ((kk * 4 + quad) ^ slotx) * 8]; \
} while (0)
#define MFMAQ(MH, NH, BF) do { \
    __builtin_amdgcn_s_setprio(1); \
    _Pragma("unroll") for (int kk = 0; kk < 2; ++kk) \
    _Pragma("unroll") for (int il = 0; il < 4; ++il) \
    _Pragma("unroll") for (int jl = 0; jl < 2; ++jl) \
        acc[(MH) * 4 + il][(NH) * 2 + jl] = __builtin_amdgcn_mfma_f32_16x16x32_bf16( \
            af[il][kk], BF[jl][kk], acc[(MH) * 4 + il][(NH) * 2 + jl], 0, 0, 0); \
    __builtin_amdgcn_s_setprio(0); \
} while (0)
#define BAR()  __builtin_amdgcn_s_barrier()
#define LGKM0() asm volatile("s_waitcnt lgkmcnt(0)" ::: "memory")

    // prologue: tile0 (A0,B0,B1,A1) + A0(1),B1(1),A1(1) = 14 GLLs
    STAGE_A(0, 0, 0);
    STAGE_B(0, 0, 0);
    STAGE_B(0, 1, 0);
    STAGE_A(0, 1, 0);
    STAGE_A(1, 0, 1);
    STAGE_B(1, 1, 1);
    STAGE_A(1, 1, 1);
    asm volatile("s_waitcnt vmcnt(6)" ::: "memory");   // tile0 landed; 6 in flight
    BAR();
    // pre-issue ph1(t=0) operands
    LOAD_A(0, 0);
    LOAD_B(0, 0, bf0v);

#pragma unroll 2
    for (int t = 0; t < NKT; ++t) {
        const int cb = t & 1;
        const int t1 = (t + 1 < NKT) ? t + 1 : NKT - 1;   // clamped tail: keeps
        const int t2 = (t + 2 < NKT) ? t + 2 : NKT - 1;   // vmcnt counts uniform
        // ---- phase 1: Q(0,0) ----
        BAR();
        LGKM0();                       // {A0,B0}(cb) reads retired (drained under prev MFMA)
        STAGE_B(cb ^ 1, 0, t1);
        MFMAQ(0, 0, bf0v);
        LOAD_B(cb, 1, bf1v);           // read-ahead for ph2
        // ---- phase 2: Q(0,1) ----
        BAR();
        LGKM0();
        STAGE_A(cb, 0, t2);            // safe: A0 reads retired by all waves at ph1 lgkm
        MFMAQ(0, 1, bf1v);
        LOAD_A(cb, 1);                 // read-ahead for ph3
        // ---- phase 3: Q(1,0) ----
        BAR();
        LGKM0();
        STAGE_B(cb, 1, t2);            // safe: B1 reads retired at ph2 lgkm
        MFMAQ(1, 0, bf0v);
        // ---- phase 4: Q(1,1) ----
        asm volatile("s_waitcnt vmcnt(4)" ::: "memory");  // retires through B0(t+1)
        BAR();
        STAGE_A(cb, 1, t2);            // safe: A1 reads retired at ph3 lgkm, after bar4
        MFMAQ(1, 1, bf1v);
        LOAD_A(cb ^ 1, 0);             // read-ahead for next tile's ph1
        LOAD_B(cb ^ 1, 0, bf0v);       // (tile t+1 fully landed via vmcnt(4)+bar)
    }
    asm volatile("s_waitcnt vmcnt(0) lgkmcnt(0)" ::: "memory");  // drain tail

    // epilogue: C row = tileM + (i>>2)*128 + wave_m*64 + (i&3)*16 + quad*4 + r
    //           C col = tileN + (j>>1)*128 + wave_n*32 + (j&1)*16 + r16
#pragma unroll
    for (int i = 0; i < 8; ++i) {
        const int row0 = tileM + (i >> 2) * 128 + wave_m * 64 + (i & 3) * 16 + quad * 4;
#pragma unroll
        for (int j = 0; j < 4; ++j) {
            const int col = tileN + (j >> 1) * 128 + wave_n * 32 + (j & 1) * 16 + r16;
            const float bv = bias[col];
#pragma unroll
            for (int r = 0; r < 4; ++r) {
                float v = acc[i][j][r] + bv;
                if (EPI == 0) {
                    ((unsigned short*)Cp)[(size_t)(row0 + r) * N + col] = f2bf(v);
                } else {
                    ((float*)Cp)[(size_t)(row0 + r) * N + col] = fmaxf(v, 0.0f);
                }
            }
        }
    }
#undef GLL
#undef STAGE_A
#undef STAGE_B
#undef LOAD_A
#undef LOAD_B
#undef MFMAQ
#undef BAR
#undef LGKM0
}

// ---------------- FUSED scan: one cooperative dispatch, u read ONCE ----------
// Grid (DD/256, SS, BB) = 2048 blocks x 256 thr = 8192 waves = exactly 32/CU.
// Requires 8 blocks/CU co-resident -> VGPR <= 64 (launch_bounds(256,8)).
// Each thread owns (channel d, chunk c): holds the chunk's TT=32 packed bf16
// pairs in 32 VGPRs across both grid syncs.
//   phase A: load w[32], local scan, write chunk-end to E.
//   sync.  phase B (blocks with c==0): in-place exclusive carry prefix over
//   chunks (1 thread per (b,d) column; independent loads pipeline).
//   sync.  phase C: read carry, rescan from register-held w, store packed
//   interleaved (re,im) uint (matches WoP's interleaved K-layout).
__global__ __launch_bounds__(256, 8)
void scan_fused(const unsigned short* __restrict__ u,
                const float* __restrict__ plog,
                float2* __restrict__ E,
                unsigned short* __restrict__ xr) {
    const int d = blockIdx.x * 256 + threadIdx.x;
    const int c = blockIdx.y, b = blockIdx.z;

    unsigned int w[TT];
    {
        const unsigned short* up = u + (size_t)(b * LL + c * TT) * (2 * DD) + 2 * d;
#pragma unroll
        for (int tl = 0; tl < TT; ++tl) { w[tl] = *(const unsigned int*)up; up += 2 * DD; }
    }
    // phase A: chunk-local scan
    {
        const float v  = expf(plog[d]);
        const float th = expf(plog[DD + d]);
        const float a  = expf(-v);
        const float lr = a * cosf(th), li = a * sinf(th);
        float zr = 0.f, zi = 0.f;
#pragma unroll
        for (int tl = 0; tl < TT; ++tl) {
            float xv = bf2f((unsigned short)(w[tl] & 0xffffu));
            float yv = bf2f((unsigned short)(w[tl] >> 16));
            float t = lr * zr - li * zi + xv;
            zi = lr * zi + li * zr + yv;
            zr = t;
        }
        E[(size_t)c * (BB * DD) + b * DD + d] = make_float2(zr, zi);
    }
    __threadfence();
    cooperative_groups::this_grid().sync();

    // phase B: exclusive carry prefix, one thread per (b,d) column
    if (c == 0) {
        const float v  = expf(plog[d]);
        const float th = expf(plog[DD + d]);
        const float aT = expf(-(float)TT * v);
        const float Lr = aT * cosf((float)TT * th), Li = aT * sinf((float)TT * th);
        float yr = 0.f, yi = 0.f;
        float2* p = E + (size_t)b * DD + d;
#pragma unroll 8
        for (int cc = 0; cc < SS; ++cc) {
            float2 e = *p;
            *p = make_float2(yr, yi);          // exclusive (in-place, 1 owner/column)
            float t = Lr * yr - Li * yi + e.x;
            yi = Lr * yi + Li * yr + e.y;
            yr = t;
            p += BB * DD;
        }
    }
    __threadfence();
    cooperative_groups::this_grid().sync();

    // phase C: rescan from registers with carry, store packed (re,im)
    {
        const float v  = expf(plog[d]);
        const float th = expf(plog[DD + d]);
        const float g  = expf(plog[2 * DD + d]);
        const float a  = expf(-v);
        const float lr = a * cosf(th), li = a * sinf(th);
        const float2 cy = E[(size_t)c * (BB * DD) + b * DD + d];
        float yr = cy.x, yi = cy.y;
        unsigned short* xp = xr + (size_t)(b * LL + c * TT) * (2 * DD) + 2 * d;
#pragma unroll
        for (int tl = 0; tl < TT; ++tl) {
            float xv = bf2f((unsigned short)(w[tl] & 0xffffu));
            float yv = bf2f((unsigned short)(w[tl] >> 16));
            float t = lr * yr - li * yi + xv;
            yi = lr * yi + li * yr + yv;
            yr = t;
            *(unsigned int*)xp = (unsigned int)f2bf(g * yr) |
                                 ((unsigned int)f2bf(g * yi) << 16);
            xp += 2 * DD;
        }
    }
}

// ---------------- fallback 3-pass scan (proven path) -------------------------
__global__ __launch_bounds__(256)
void scanA(const unsigned short* __restrict__ u,
           const float* __restrict__ plog,
           float2* __restrict__ Eend) {
    const int d = blockIdx.x * 256 + threadIdx.x;
    const int c = blockIdx.y, b = blockIdx.z;
    const float v  = expf(plog[d]);
    const float th = expf(plog[DD + d]);
    const float a  = expf(-v);
    const float lr = a * cosf(th), li = a * sinf(th);
    float zr = 0.f, zi = 0.f;
    const unsigned short* up = u + (size_t)(b * LL + c * TT) * (2 * DD) + 2 * d;
#pragma unroll 8
    for (int tl = 0; tl < TT; ++tl) {
        unsigned int pr = *(const unsigned int*)up;
        float xr = bf2f((unsigned short)(pr & 0xffffu));
        float xi = bf2f((unsigned short)(pr >> 16));
        float t = lr * zr - li * zi + xr;
        zi = lr * zi + li * zr + xi;
        zr = t;
        up += 2 * DD;
    }
    Eend[(size_t)c * (BB * DD) + b * DD + d] = make_float2(zr, zi);
}

__global__ __launch_bounds__(256)
void scanB(const float* __restrict__ plog, float2* __restrict__ E) {
    const int i = blockIdx.x * 256 + threadIdx.x;   // i = b*DD + d
    const int d = i & (DD - 1);
    const float v  = expf(plog[d]);
    const float th = expf(plog[DD + d]);
    const float aT = expf(-(float)TT * v);
    const float Lr = aT * cosf((float)TT * th), Li = aT * sinf((float)TT * th);
    float yr = 0.f, yi = 0.f;
    float2* p = E + i;
#pragma unroll 8
    for (int c = 0; c < SS; ++c) {
        float2 e = *p;
        *p = make_float2(yr, yi);
        float t = Lr * yr - Li * yi + e.x;
        yi = Lr * yi + Li * yr + e.y;
        yr = t;
        p += BB * DD;
    }
}

__global__ __launch_bounds__(256)
void scanC(const unsigned short* __restrict__ u,
           const float* __restrict__ plog,
           const float2* __restrict__ Carry,
           unsigned short* __restrict__ xr) {
    const int d = blockIdx.x * 256 + threadIdx.x;
    const int c = blockIdx.y, b = blockIdx.z;
    const float v  = expf(plog[d]);
    const float th = expf(plog[DD + d]);
    const float g  = expf(plog[2 * DD + d]);
    const float a  = expf(-v);
    const float lr = a * cosf(th), li = a * sinf(th);
    const float2 cy = Carry[(size_t)c * (BB * DD) + b * DD + d];
    float yr = cy.x, yi = cy.y;
    const unsigned short* up = u + (size_t)(b * LL + c * TT) * (2 * DD) + 2 * d;
    unsigned short* xp = xr + (size_t)(b * LL + c * TT) * (2 * DD) + 2 * d;
#pragma unroll 8
    for (int tl = 0; tl < TT; ++tl) {
        unsigned int pr = *(const unsigned int*)up;
        float xrv = bf2f((unsigned short)(pr & 0xffffu));
        float xiv = bf2f((unsigned short)(pr >> 16));
        float t = lr * yr - li * yi + xrv;
        yi = lr * yi + li * yr + xiv;
        yr = t;
        *(unsigned int*)xp = (unsigned int)f2bf(g * yr) |
                             ((unsigned int)f2bf(g * yi) << 16);
        up += 2 * DD;
        xp += 2 * DD;
    }
}

extern "C" void kernel_launch(void* const* d_in, const int* in_sizes, int n_in,
                              void* d_out, int out_size, void* d_ws, size_t ws_size,
                              hipStream_t stream) {
    const float* inputs = (const float*)d_in[0];   // B*L*D = 16777216
    const float* Wi     = (const float*)d_in[1];   // 2D*D  = 2097152
    const float* bi     = (const float*)d_in[2];   // 2D
    const float* Wo     = (const float*)d_in[3];   // D*2D  = 2097152
    const float* bo     = (const float*)d_in[4];   // D
    const float* plog   = (const float*)d_in[5];   // 3*D
    float* out = (float*)d_out;

    const size_t M = (size_t)BB * LL;              // 16384
    unsigned short* u_bf  = (unsigned short*)d_ws;             // M*2D bf16  (64 MB)
    unsigned short* xr_bf = u_bf  + M * 2 * DD;                // M*2D bf16  (64 MB)
    unsigned short* in_bf = xr_bf + M * 2 * DD;                // M*D  bf16  (32 MB)
    unsigned short* Wi_bf = in_bf + M * DD;                    // 2D*D bf16  (4 MB)
    unsigned short* Wo_bf = Wi_bf + (size_t)2 * DD * DD;       // D*2D bf16  (4 MB)
    // Eend/Carry (SS*B*D float2 = 4 MB) aliases in_bf: in_bf is dead after
    // GEMM1 completes, and the scan (first Eend writer) runs after GEMM1.
    float2* Eend = (float2*)in_bf;

    // merged bf16 casts (inputs + Wi + Wo-interleaved) in one dispatch
    {
        int total = NIN4 + NWI4 + NWO8;            // 4980736, divisible by 256
        cast_all_kernel<<<total / 256, 256, 0, stream>>>(
            (const float4*)inputs, (ushort4*)in_bf,
            (const float4*)Wi,     (ushort4*)Wi_bf,
            Wo,                    Wo_bf);
    }

    // GEMM1: u[M, 2D] = in_bf[M, D] @ Wi^T + bi   (bf16 out), N=2048 -> NT=8
    gemm256<DD, 8, 0><<<(M / 256) * 8, 512, 0, stream>>>(
        in_bf, Wi_bf, bi, (void*)u_bf);

    // scan: fused cooperative single-pass if co-residency holds (needs 8
    // blocks/CU, i.e. VGPR <= 64); else proven 3-kernel path.
    bool coop = false;
    {
        int nb = 0;
        hipError_t qe = hipOccupancyMaxActiveBlocksPerMultiprocessor(&nb, scan_fused, 256, 0);
        if (qe == hipSuccess && nb >= 8) {
            const unsigned short* u_arg = u_bf;
            const float* p_arg = plog;
            float2* e_arg = Eend;
            unsigned short* x_arg = xr_bf;
            void* args[] = { (void*)&u_arg, (void*)&p_arg, (void*)&e_arg, (void*)&x_arg };
            hipError_t le = hipLaunchCooperativeKernel(scan_fused,
                dim3(DD / 256, SS, BB), dim3(256), args, 0, stream);
            coop = (le == hipSuccess);
        }
    }
    if (!coop) {
        scanA<<<dim3(DD / 256, SS, BB), 256, 0, stream>>>(u_bf, plog, Eend);
        scanB<<<(BB * DD) / 256, 256, 0, stream>>>(plog, Eend);
        scanC<<<dim3(DD / 256, SS, BB), 256, 0, stream>>>(u_bf, plog, Eend, xr_bf);
    }

    // GEMM2: out[M, D] = relu(xr[M, 2D] @ WoP^T + bo)  (f32 out), N=1024 -> NT=4
    gemm256<2 * DD, 4, 1><<<(M / 256) * 4, 512, 0, stream>>>(
        xr_bf, Wo_bf, bo, (void*)out);
}

// Round 8
// 293.871 us; speedup vs baseline: 1.0445x; 1.0232x over previous
//
#include <hip/hip_runtime.h>
#include <hip/hip_cooperative_groups.h>

// Problem constants (B, L_IN, D) = (4, 4096, 1024)
#define BB 4
#define LL 4096
#define DD 1024
#define SS 64   // number of chunks in the scan
#define TT 64   // chunk length (SS*TT == LL)

typedef __attribute__((ext_vector_type(4))) float  floatx4;
typedef __attribute__((ext_vector_type(8))) short  shortx8;
typedef __attribute__((ext_vector_type(8))) unsigned short ushortx8;

static __device__ __forceinline__ unsigned short f2bf(float f) {
    unsigned int u = __float_as_uint(f);
    u += 0x7fffu + ((u >> 16) & 1u);           // round-to-nearest-even
    return (unsigned short)(u >> 16);
}
static __device__ __forceinline__ float bf2f(unsigned short h) {
    return __uint_as_float(((unsigned int)h) << 16);
}

// ---------------- merged f32 -> bf16 cast (inputs + Wi + Wo-interleaved) ----
// Wo is cast WITH K-column interleave: WoP[n][2d] = Wo[n][d] (re),
// WoP[n][2d+1] = Wo[n][DD+d] (im). xr is produced in the same interleaved
// K-layout by the scan, so GEMM2 (out = xr @ Wo^T) is unchanged semantically.
#define NIN4 (BB * LL * DD / 4)          // 4194304
#define NWI4 (2 * DD * DD / 4)           // 524288
#define NWO8 (DD * DD / 4)               // 262144 (8 outputs/thread)
__global__ void cast_all_kernel(const float4* __restrict__ s_in, ushort4* __restrict__ d_inb,
                                const float4* __restrict__ s_wi, ushort4* __restrict__ d_wib,
                                const float* __restrict__ s_wo, unsigned short* __restrict__ d_wob) {
    int i = blockIdx.x * blockDim.x + threadIdx.x;
    if (i < NIN4 + NWI4) {
        const float4* s; ushort4* d; int j;
        if (i < NIN4) { s = s_in; d = d_inb; j = i; }
        else          { s = s_wi; d = d_wib; j = i - NIN4; }
        float4 v = s[j];
        ushort4 o;
        o.x = f2bf(v.x); o.y = f2bf(v.y); o.z = f2bf(v.z); o.w = f2bf(v.w);
        d[j] = o;
    } else {
        int j = i - NIN4 - NWI4;               // j < NWO8
        int n  = j >> 8;                       // row (DD/4 = 256 quads per row)
        int d0 = (j & 255) * 4;
        const float* rowp = s_wo + (size_t)n * (2 * DD);
        float4 re = *(const float4*)(rowp + d0);
        float4 im = *(const float4*)(rowp + DD + d0);
        ushortx8 o;
        o[0] = f2bf(re.x); o[1] = f2bf(im.x);
        o[2] = f2bf(re.y); o[3] = f2bf(im.y);
        o[4] = f2bf(re.z); o[5] = f2bf(im.z);
        o[6] = f2bf(re.w); o[7] = f2bf(im.w);
        *(ushortx8*)(d_wob + (size_t)n * (2 * DD) + 2 * d0) = o;
    }
}

// ---------------- bf16 GEMM: C[M,N] = A[M,K] * B[N,K]^T + bias ----------------
// 256x256 tile, BK=64, 512 threads = 8 waves (2M x 4N), per-wave 128x64 output.
// READ-AHEAD 4-phase schedule (best measured r2 variant): each phase issues the
// NEXT phase's ds_reads AFTER its MFMA cluster, so read drain hides under MFMA
// + barrier; one raw s_barrier per phase; counted vmcnt(4) once per K-tile.
//
// Hazard proof (semantic, no timing assumptions). R(p) = reads pending at
// phase p top (issued end of p-1); S(p) = region staged in phase p.
//   R(ph1)={A0,B0}(cb)  R(ph2)={B1(cb)}  R(ph3)={A1(cb)}  R(ph4)={}
//   S(ph1)=B0(cb^1,t+1) S(ph2)=A0(cb,t+2) S(ph3)=B1(cb,t+2) S(ph4)=A1(cb,t+2)
// 1) S(p) ∩ R(p) = ∅ and S(p) ∩ R(p+1) = ∅ for all p.
// 2) Every S(p) overwriting a previously-read region is issued after a barrier
//    whose arrival implies all waves retired those reads via lgkmcnt(0).
// 3) vmcnt(4) before bar4 retires everything through S(ph1)=B0(t+1);
//    end-of-ph4 reads {A0,B0}(cb^1,t+1) are issued after bar4.
//
// LDS chunk swizzle (verified, 0 bank conflicts): within each 128-row
// half-tile, chunk q holds row=q>>3, k8=(q&7)^(row&7); reads XOR with r16&7.
template<int K, int NT, int EPI>
__global__ __launch_bounds__(512, 2)
void gemm256(const unsigned short* __restrict__ A,
             const unsigned short* __restrict__ B,
             const float* __restrict__ bias,
             void* __restrict__ Cp) {
    constexpr int N   = NT * 256;
    constexpr int NKT = K / 64;            // 16 or 32 here
    __shared__ __align__(16) short As[2][256 * 64];   // 64 KB
    __shared__ __align__(16) short Bs[2][256 * 64];   // 64 KB

    const int tid = threadIdx.x;
    const int blk = blockIdx.x;
    const int xcd = blk & 7;
    const int i2  = blk >> 3;
    const int tileM = ((i2 / NT) * 8 + xcd) * 256;
    const int tileN = (i2 % NT) * 256;

    const int lane   = tid & 63;
    const int wave   = tid >> 6;
    const int wave_m = wave >> 2;          // 0..1
    const int wave_n = wave & 3;           // 0..3
    const int r16    = lane & 15;
    const int quad   = lane >> 4;
    const int slotx  = r16 & 7;
    const int wmRow  = wave_m * 64 + r16;
    const int wnRow  = wave_n * 32 + r16;

    const int srow = tid >> 3;                         // 0..63
    const int scol = ((tid & 7) ^ (srow & 7)) * 8;     // pre-swizzled k offset (shorts)
    const int ldsChunkBase = (tid & ~63) * 8;          // shorts
    const size_t aOff = (size_t)(tileM + srow) * K + scol;
    const size_t bOff = (size_t)(tileN + srow) * K + scol;

    floatx4 acc[8][4] = {};
    shortx8 af[4][2], bf0v[2][2], bf1v[2][2];

#define GLL(SRC, DST) __builtin_amdgcn_global_load_lds( \
        (const __attribute__((address_space(1))) void*)(SRC), \
        (__attribute__((address_space(3))) void*)(DST), 16, 0, 0)
#define STAGE_A(BUF, H, KT) do { \
    GLL(A + aOff + (size_t)((H) * 128) * K + (KT) * 64,      &As[BUF][(H) * 8192 + ldsChunkBase]); \
    GLL(A + aOff + (size_t)((H) * 128 + 64) * K + (KT) * 64, &As[BUF][(H) * 8192 + 4096 + ldsChunkBase]); \
} while (0)
#define STAGE_B(BUF, H, KT) do { \
    GLL(B + bOff + (size_t)((H) * 128) * K + (KT) * 64,      &Bs[BUF][(H) * 8192 + ldsChunkBase]); \
    GLL(B + bOff + (size_t)((H) * 128 + 64) * K + (KT) * 64, &Bs[BUF][(H) * 8192 + 4096 + ldsChunkBase]); \
} while (0)
#define LOAD_A(BUF, MH) do { \
    _Pragma("unroll") for (int il = 0; il < 4; ++il) \
    _Pragma("unroll") for (int kk = 0; kk < 2; ++kk) \
        af[il][kk] = *(const shortx8*)&As[BUF][((MH) * 128 + wmRow + il * 16) * 64 + ((kk * 4 + quad) ^ slotx) * 8]; \
} while (0)
#define LOAD_B(BUF, NH, DST) do { \
    _Pragma("unroll") for (int jl = 0; jl < 2; ++jl) \
    _Pragma("unroll") for (int kk = 0; kk < 2; ++kk) \
        DST[jl][kk] = *(const shortx8*)&Bs[BUF][((NH) * 128 + wnRow + jl * 16) * 64 + ((kk * 4 + quad) ^ slotx) * 8]; \
} while (0)
#define MFMAQ(MH, NH, BF) do { \
    __builtin_amdgcn_s_setprio(1); \
    _Pragma("unroll") for (int kk = 0; kk < 2; ++kk) \
    _Pragma("unroll") for (int il = 0; il < 4; ++il) \
    _Pragma("unroll") for (int jl = 0; jl < 2; ++jl) \
        acc[(MH) * 4 + il][(NH) * 2 + jl] = __builtin_amdgcn_mfma_f32_16x16x32_bf16( \
            af[il][kk], BF[jl][kk], acc[(MH) * 4 + il][(NH) * 2 + jl], 0, 0, 0); \
    __builtin_amdgcn_s_setprio(0); \
} while (0)
#define BAR()  __builtin_amdgcn_s_barrier()
#define LGKM0() asm volatile("s_waitcnt lgkmcnt(0)" ::: "memory")

    // prologue: tile0 (A0,B0,B1,A1) + A0(1),B1(1),A1(1) = 14 GLLs
    STAGE_A(0, 0, 0);
    STAGE_B(0, 0, 0);
    STAGE_B(0, 1, 0);
    STAGE_A(0, 1, 0);
    STAGE_A(1, 0, 1);
    STAGE_B(1, 1, 1);
    STAGE_A(1, 1, 1);
    asm volatile("s_waitcnt vmcnt(6)" ::: "memory");   // tile0 landed; 6 in flight
    BAR();
    // pre-issue ph1(t=0) operands
    LOAD_A(0, 0);
    LOAD_B(0, 0, bf0v);

#pragma unroll 2
    for (int t = 0; t < NKT; ++t) {
        const int cb = t & 1;
        const int t1 = (t + 1 < NKT) ? t + 1 : NKT - 1;   // clamped tail: keeps
        const int t2 = (t + 2 < NKT) ? t + 2 : NKT - 1;   // vmcnt counts uniform
        // ---- phase 1: Q(0,0) ----
        BAR();
        LGKM0();                       // {A0,B0}(cb) reads retired (drained under prev MFMA)
        STAGE_B(cb ^ 1, 0, t1);
        MFMAQ(0, 0, bf0v);
        LOAD_B(cb, 1, bf1v);           // read-ahead for ph2
        // ---- phase 2: Q(0,1) ----
        BAR();
        LGKM0();
        STAGE_A(cb, 0, t2);            // safe: A0 reads retired by all waves at ph1 lgkm
        MFMAQ(0, 1, bf1v);
        LOAD_A(cb, 1);                 // read-ahead for ph3
        // ---- phase 3: Q(1,0) ----
        BAR();
        LGKM0();
        STAGE_B(cb, 1, t2);            // safe: B1 reads retired at ph2 lgkm
        MFMAQ(1, 0, bf0v);
        // ---- phase 4: Q(1,1) ----
        asm volatile("s_waitcnt vmcnt(4)" ::: "memory");  // retires through B0(t+1)
        BAR();
        STAGE_A(cb, 1, t2);            // safe: A1 reads retired at ph3 lgkm, after bar4
        MFMAQ(1, 1, bf1v);
        LOAD_A(cb ^ 1, 0);             // read-ahead for next tile's ph1
        LOAD_B(cb ^ 1, 0, bf0v);       // (tile t+1 fully landed via vmcnt(4)+bar)
    }
    asm volatile("s_waitcnt vmcnt(0) lgkmcnt(0)" ::: "memory");  // drain tail

    // epilogue: C row = tileM + (i>>2)*128 + wave_m*64 + (i&3)*16 + quad*4 + r
    //           C col = tileN + (j>>1)*128 + wave_n*32 + (j&1)*16 + r16
#pragma unroll
    for (int i = 0; i < 8; ++i) {
        const int row0 = tileM + (i >> 2) * 128 + wave_m * 64 + (i & 3) * 16 + quad * 4;
#pragma unroll
        for (int j = 0; j < 4; ++j) {
            const int col = tileN + (j >> 1) * 128 + wave_n * 32 + (j & 1) * 16 + r16;
            const float bv = bias[col];
#pragma unroll
            for (int r = 0; r < 4; ++r) {
                float v = acc[i][j][r] + bv;
                if (EPI == 0) {
                    ((unsigned short*)Cp)[(size_t)(row0 + r) * N + col] = f2bf(v);
                } else {
                    ((float*)Cp)[(size_t)(row0 + r) * N + col] = fmaxf(v, 0.0f);
                }
            }
        }
    }
#undef GLL
#undef STAGE_A
#undef STAGE_B
#undef LOAD_A
#undef LOAD_B
#undef MFMAQ
#undef BAR
#undef LGKM0
}

// ---------------- FUSED scan: one cooperative dispatch, u read ONCE ----------
// TT=64/SS=64: grid (DD/256, SS, BB) = 1024 blocks = EXACTLY 4 blocks/CU.
// launch_bounds(256,4) -> VGPR budget 128: w[64] (64 VGPRs) + ~30 live state
// fits WITHOUT spill (r7's (256,8)/64-VGPR bound spilled w[] to scratch —
// VGPR_Count was 32; this round's alarm check is VGPR ~95-115, localMem 0).
// Each thread owns (channel d, chunk c): holds the chunk's TT packed bf16
// pairs in VGPRs across both grid syncs; 64 independent unrolled loads give
// the ILP that covers HBM latency at 4 waves/SIMD.
//   phase A: load w[64], local scan, write chunk-end to E.
//   sync.  phase B (c==0 blocks, 4096 threads): in-place exclusive carry
//   prefix over the 64 chunks (1 thread per (b,d) column).
//   sync.  phase C: read carry, rescan from register-held w, store packed
//   interleaved (re,im) uint (matches WoP's interleaved K-layout).
__global__ __launch_bounds__(256, 4)
void scan_fused(const unsigned short* __restrict__ u,
                const float* __restrict__ plog,
                float2* __restrict__ E,
                unsigned short* __restrict__ xr) {
    const int d = blockIdx.x * 256 + threadIdx.x;
    const int c = blockIdx.y, b = blockIdx.z;

    unsigned int w[TT];
    {
        const unsigned short* up = u + (size_t)(b * LL + c * TT) * (2 * DD) + 2 * d;
#pragma unroll
        for (int tl = 0; tl < TT; ++tl) { w[tl] = *(const unsigned int*)up; up += 2 * DD; }
    }
    // phase A: chunk-local scan
    {
        const float v  = expf(plog[d]);
        const float th = expf(plog[DD + d]);
        const float a  = expf(-v);
        const float lr = a * cosf(th), li = a * sinf(th);
        float zr = 0.f, zi = 0.f;
#pragma unroll
        for (int tl = 0; tl < TT; ++tl) {
            float xv = bf2f((unsigned short)(w[tl] & 0xffffu));
            float yv = bf2f((unsigned short)(w[tl] >> 16));
            float t = lr * zr - li * zi + xv;
            zi = lr * zi + li * zr + yv;
            zr = t;
        }
        E[(size_t)c * (BB * DD) + b * DD + d] = make_float2(zr, zi);
    }
    __threadfence();
    cooperative_groups::this_grid().sync();

    // phase B: exclusive carry prefix, one thread per (b,d) column
    if (c == 0) {
        const float v  = expf(plog[d]);
        const float th = expf(plog[DD + d]);
        const float aT = expf(-(float)TT * v);
        const float Lr = aT * cosf((float)TT * th), Li = aT * sinf((float)TT * th);
        float yr = 0.f, yi = 0.f;
        float2* p = E + (size_t)b * DD + d;
#pragma unroll 8
        for (int cc = 0; cc < SS; ++cc) {
            float2 e = *p;
            *p = make_float2(yr, yi);          // exclusive (in-place, 1 owner/column)
            float t = Lr * yr - Li * yi + e.x;
            yi = Lr * yi + Li * yr + e.y;
            yr = t;
            p += BB * DD;
        }
    }
    __threadfence();
    cooperative_groups::this_grid().sync();

    // phase C: rescan from registers with carry, store packed (re,im)
    {
        const float v  = expf(plog[d]);
        const float th = expf(plog[DD + d]);
        const float g  = expf(plog[2 * DD + d]);
        const float a  = expf(-v);
        const float lr = a * cosf(th), li = a * sinf(th);
        const float2 cy = E[(size_t)c * (BB * DD) + b * DD + d];
        float yr = cy.x, yi = cy.y;
        unsigned short* xp = xr + (size_t)(b * LL + c * TT) * (2 * DD) + 2 * d;
#pragma unroll
        for (int tl = 0; tl < TT; ++tl) {
            float xv = bf2f((unsigned short)(w[tl] & 0xffffu));
            float yv = bf2f((unsigned short)(w[tl] >> 16));
            float t = lr * yr - li * yi + xv;
            yi = lr * yi + li * yr + yv;
            yr = t;
            *(unsigned int*)xp = (unsigned int)f2bf(g * yr) |
                                 ((unsigned int)f2bf(g * yi) << 16);
            xp += 2 * DD;
        }
    }
}

// ---------------- fallback 3-pass scan (proven path) -------------------------
__global__ __launch_bounds__(256)
void scanA(const unsigned short* __restrict__ u,
           const float* __restrict__ plog,
           float2* __restrict__ Eend) {
    const int d = blockIdx.x * 256 + threadIdx.x;
    const int c = blockIdx.y, b = blockIdx.z;
    const float v  = expf(plog[d]);
    const float th = expf(plog[DD + d]);
    const float a  = expf(-v);
    const float lr = a * cosf(th), li = a * sinf(th);
    float zr = 0.f, zi = 0.f;
    const unsigned short* up = u + (size_t)(b * LL + c * TT) * (2 * DD) + 2 * d;
#pragma unroll 8
    for (int tl = 0; tl < TT; ++tl) {
        unsigned int pr = *(const unsigned int*)up;
        float xr = bf2f((unsigned short)(pr & 0xffffu));
        float xi = bf2f((unsigned short)(pr >> 16));
        float t = lr * zr - li * zi + xr;
        zi = lr * zi + li * zr + xi;
        zr = t;
        up += 2 * DD;
    }
    Eend[(size_t)c * (BB * DD) + b * DD + d] = make_float2(zr, zi);
}

__global__ __launch_bounds__(256)
void scanB(const float* __restrict__ plog, float2* __restrict__ E) {
    const int i = blockIdx.x * 256 + threadIdx.x;   // i = b*DD + d
    const int d = i & (DD - 1);
    const float v  = expf(plog[d]);
    const float th = expf(plog[DD + d]);
    const float aT = expf(-(float)TT * v);
    const float Lr = aT * cosf((float)TT * th), Li = aT * sinf((float)TT * th);
    float yr = 0.f, yi = 0.f;
    float2* p = E + i;
#pragma unroll 8
    for (int c = 0; c < SS; ++c) {
        float2 e = *p;
        *p = make_float2(yr, yi);
        float t = Lr * yr - Li * yi + e.x;
        yi = Lr * yi + Li * yr + e.y;
        yr = t;
        p += BB * DD;
    }
}

__global__ __launch_bounds__(256)
void scanC(const unsigned short* __restrict__ u,
           const float* __restrict__ plog,
           const float2* __restrict__ Carry,
           unsigned short* __restrict__ xr) {
    const int d = blockIdx.x * 256 + threadIdx.x;
    const int c = blockIdx.y, b = blockIdx.z;
    const float v  = expf(plog[d]);
    const float th = expf(plog[DD + d]);
    const float g  = expf(plog[2 * DD + d]);
    const float a  = expf(-v);
    const float lr = a * cosf(th), li = a * sinf(th);
    const float2 cy = Carry[(size_t)c * (BB * DD) + b * DD + d];
    float yr = cy.x, yi = cy.y;
    const unsigned short* up = u + (size_t)(b * LL + c * TT) * (2 * DD) + 2 * d;
    unsigned short* xp = xr + (size_t)(b * LL + c * TT) * (2 * DD) + 2 * d;
#pragma unroll 8
    for (int tl = 0; tl < TT; ++tl) {
        unsigned int pr = *(const unsigned int*)up;
        float xrv = bf2f((unsigned short)(pr & 0xffffu));
        float xiv = bf2f((unsigned short)(pr >> 16));
        float t = lr * yr - li * yi + xrv;
        yi = lr * yi + li * yr + xiv;
        yr = t;
        *(unsigned int*)xp = (unsigned int)f2bf(g * yr) |
                             ((unsigned int)f2bf(g * yi) << 16);
        up += 2 * DD;
        xp += 2 * DD;
    }
}

extern "C" void kernel_launch(void* const* d_in, const int* in_sizes, int n_in,
                              void* d_out, int out_size, void* d_ws, size_t ws_size,
                              hipStream_t stream) {
    const float* inputs = (const float*)d_in[0];   // B*L*D = 16777216
    const float* Wi     = (const float*)d_in[1];   // 2D*D  = 2097152
    const float* bi     = (const float*)d_in[2];   // 2D
    const float* Wo     = (const float*)d_in[3];   // D*2D  = 2097152
    const float* bo     = (const float*)d_in[4];   // D
    const float* plog   = (const float*)d_in[5];   // 3*D
    float* out = (float*)d_out;

    const size_t M = (size_t)BB * LL;              // 16384
    unsigned short* u_bf  = (unsigned short*)d_ws;             // M*2D bf16  (64 MB)
    unsigned short* xr_bf = u_bf  + M * 2 * DD;                // M*2D bf16  (64 MB)
    unsigned short* in_bf = xr_bf + M * 2 * DD;                // M*D  bf16  (32 MB)
    unsigned short* Wi_bf = in_bf + M * DD;                    // 2D*D bf16  (4 MB)
    unsigned short* Wo_bf = Wi_bf + (size_t)2 * DD * DD;       // D*2D bf16  (4 MB)
    // Eend/Carry (SS*B*D float2 = 2 MB) aliases in_bf: in_bf is dead after
    // GEMM1 completes, and the scan (first Eend writer) runs after GEMM1.
    float2* Eend = (float2*)in_bf;

    // merged bf16 casts (inputs + Wi + Wo-interleaved) in one dispatch
    {
        int total = NIN4 + NWI4 + NWO8;            // 4980736, divisible by 256
        cast_all_kernel<<<total / 256, 256, 0, stream>>>(
            (const float4*)inputs, (ushort4*)in_bf,
            (const float4*)Wi,     (ushort4*)Wi_bf,
            Wo,                    Wo_bf);
    }

    // GEMM1: u[M, 2D] = in_bf[M, D] @ Wi^T + bi   (bf16 out), N=2048 -> NT=8
    gemm256<DD, 8, 0><<<(M / 256) * 8, 512, 0, stream>>>(
        in_bf, Wi_bf, bi, (void*)u_bf);

    // scan: fused cooperative single-pass if co-residency holds (needs 4
    // blocks/CU at 1024 blocks); else proven 3-kernel path.
    bool coop = false;
    {
        int nb = 0;
        hipError_t qe = hipOccupancyMaxActiveBlocksPerMultiprocessor(&nb, scan_fused, 256, 0);
        if (qe == hipSuccess && nb >= 4) {
            const unsigned short* u_arg = u_bf;
            const float* p_arg = plog;
            float2* e_arg = Eend;
            unsigned short* x_arg = xr_bf;
            void* args[] = { (void*)&u_arg, (void*)&p_arg, (void*)&e_arg, (void*)&x_arg };
            hipError_t le = hipLaunchCooperativeKernel(scan_fused,
                dim3(DD / 256, SS, BB), dim3(256), args, 0, stream);
            coop = (le == hipSuccess);
        }
    }
    if (!coop) {
        scanA<<<dim3(DD / 256, SS, BB), 256, 0, stream>>>(u_bf, plog, Eend);
        scanB<<<(BB * DD) / 256, 256, 0, stream>>>(plog, Eend);
        scanC<<<dim3(DD / 256, SS, BB), 256, 0, stream>>>(u_bf, plog, Eend, xr_bf);
    }

    // GEMM2: out[M, D] = relu(xr[M, 2D] @ WoP^T + bo)  (f32 out), N=1024 -> NT=4
    gemm256<2 * DD, 4, 1><<<(M / 256) * 4, 512, 0, stream>>>(
        xr_bf, Wo_bf, bo, (void*)out);
}

// Round 9
// 290.919 us; speedup vs baseline: 1.0551x; 1.0101x over previous
//
#include <hip/hip_runtime.h>

// Problem constants (B, L_IN, D) = (4, 4096, 1024)
#define BB 4
#define LL 4096
#define DD 1024
#define SS 64   // number of chunks in the scan
#define TT 64   // chunk length (SS*TT == LL)
#define NCH 16  // chains: (DD/256) * BB

typedef __attribute__((ext_vector_type(4))) float  floatx4;
typedef __attribute__((ext_vector_type(8))) short  shortx8;
typedef __attribute__((ext_vector_type(8))) unsigned short ushortx8;

static __device__ __forceinline__ unsigned short f2bf(float f) {
    unsigned int u = __float_as_uint(f);
    u += 0x7fffu + ((u >> 16) & 1u);           // round-to-nearest-even
    return (unsigned short)(u >> 16);
}
static __device__ __forceinline__ float bf2f(unsigned short h) {
    return __uint_as_float(((unsigned int)h) << 16);
}

// ---------------- merged f32 -> bf16 cast (inputs + Wi + Wo-interleaved) ----
// Also zeroes the scan flag array (runs before GEMM1 -> visible by scan time).
#define NIN4 (BB * LL * DD / 4)          // 4194304
#define NWI4 (2 * DD * DD / 4)           // 524288
#define NWO8 (DD * DD / 4)               // 262144 (8 outputs/thread)
__global__ void cast_all_kernel(const float4* __restrict__ s_in, ushort4* __restrict__ d_inb,
                                const float4* __restrict__ s_wi, ushort4* __restrict__ d_wib,
                                const float* __restrict__ s_wo, unsigned short* __restrict__ d_wob,
                                int* __restrict__ flags) {
    int i = blockIdx.x * blockDim.x + threadIdx.x;
    if (i < NCH * SS) flags[i] = 0;
    if (i < NIN4 + NWI4) {
        const float4* s; ushort4* d; int j;
        if (i < NIN4) { s = s_in; d = d_inb; j = i; }
        else          { s = s_wi; d = d_wib; j = i - NIN4; }
        float4 v = s[j];
        ushort4 o;
        o.x = f2bf(v.x); o.y = f2bf(v.y); o.z = f2bf(v.z); o.w = f2bf(v.w);
        d[j] = o;
    } else {
        int j = i - NIN4 - NWI4;               // j < NWO8
        int n  = j >> 8;                       // row (DD/4 = 256 quads per row)
        int d0 = (j & 255) * 4;
        const float* rowp = s_wo + (size_t)n * (2 * DD);
        float4 re = *(const float4*)(rowp + d0);
        float4 im = *(const float4*)(rowp + DD + d0);
        ushortx8 o;
        o[0] = f2bf(re.x); o[1] = f2bf(im.x);
        o[2] = f2bf(re.y); o[3] = f2bf(im.y);
        o[4] = f2bf(re.z); o[5] = f2bf(im.z);
        o[6] = f2bf(re.w); o[7] = f2bf(im.w);
        *(ushortx8*)(d_wob + (size_t)n * (2 * DD) + 2 * d0) = o;
    }
}

// ---------------- bf16 GEMM: C[M,N] = A[M,K] * B[N,K]^T + bias ----------------
// (unchanged r2/r8 proven kernel; see hazard proof in earlier rounds)
template<int K, int NT, int EPI>
__global__ __launch_bounds__(512, 2)
void gemm256(const unsigned short* __restrict__ A,
             const unsigned short* __restrict__ B,
             const float* __restrict__ bias,
             void* __restrict__ Cp) {
    constexpr int N   = NT * 256;
    constexpr int NKT = K / 64;            // 16 or 32 here
    __shared__ __align__(16) short As[2][256 * 64];   // 64 KB
    __shared__ __align__(16) short Bs[2][256 * 64];   // 64 KB

    const int tid = threadIdx.x;
    const int blk = blockIdx.x;
    const int xcd = blk & 7;
    const int i2  = blk >> 3;
    const int tileM = ((i2 / NT) * 8 + xcd) * 256;
    const int tileN = (i2 % NT) * 256;

    const int lane   = tid & 63;
    const int wave   = tid >> 6;
    const int wave_m = wave >> 2;          // 0..1
    const int wave_n = wave & 3;           // 0..3
    const int r16    = lane & 15;
    const int quad   = lane >> 4;
    const int slotx  = r16 & 7;
    const int wmRow  = wave_m * 64 + r16;
    const int wnRow  = wave_n * 32 + r16;

    const int srow = tid >> 3;                         // 0..63
    const int scol = ((tid & 7) ^ (srow & 7)) * 8;     // pre-swizzled k offset (shorts)
    const int ldsChunkBase = (tid & ~63) * 8;          // shorts
    const size_t aOff = (size_t)(tileM + srow) * K + scol;
    const size_t bOff = (size_t)(tileN + srow) * K + scol;

    floatx4 acc[8][4] = {};
    shortx8 af[4][2], bf0v[2][2], bf1v[2][2];

#define GLL(SRC, DST) __builtin_amdgcn_global_load_lds( \
        (const __attribute__((address_space(1))) void*)(SRC), \
        (__attribute__((address_space(3))) void*)(DST), 16, 0, 0)
#define STAGE_A(BUF, H, KT) do { \
    GLL(A + aOff + (size_t)((H) * 128) * K + (KT) * 64,      &As[BUF][(H) * 8192 + ldsChunkBase]); \
    GLL(A + aOff + (size_t)((H) * 128 + 64) * K + (KT) * 64, &As[BUF][(H) * 8192 + 4096 + ldsChunkBase]); \
} while (0)
#define STAGE_B(BUF, H, KT) do { \
    GLL(B + bOff + (size_t)((H) * 128) * K + (KT) * 64,      &Bs[BUF][(H) * 8192 + ldsChunkBase]); \
    GLL(B + bOff + (size_t)((H) * 128 + 64) * K + (KT) * 64, &Bs[BUF][(H) * 8192 + 4096 + ldsChunkBase]); \
} while (0)
#define LOAD_A(BUF, MH) do { \
    _Pragma("unroll") for (int il = 0; il < 4; ++il) \
    _Pragma("unroll") for (int kk = 0; kk < 2; ++kk) \
        af[il][kk] = *(const shortx8*)&As[BUF][((MH) * 128 + wmRow + il * 16) * 64 + ((kk * 4 + quad) ^ slotx) * 8]; \
} while (0)
#define LOAD_B(BUF, NH, DST) do { \
    _Pragma("unroll") for (int jl = 0; jl < 2; ++jl) \
    _Pragma("unroll") for (int kk = 0; kk < 2; ++kk) \
        DST[jl][kk] = *(const shortx8*)&Bs[BUF][((NH) * 128 + wnRow + jl * 16) * 64 + ((kk * 4 + quad) ^ slotx) * 8]; \
} while (0)
#define MFMAQ(MH, NH, BF) do { \
    __builtin_amdgcn_s_setprio(1); \
    _Pragma("unroll") for (int kk = 0; kk < 2; ++kk) \
    _Pragma("unroll") for (int il = 0; il < 4; ++il) \
    _Pragma("unroll") for (int jl = 0; jl < 2; ++jl) \
        acc[(MH) * 4 + il][(NH) * 2 + jl] = __builtin_amdgcn_mfma_f32_16x16x32_bf16( \
            af[il][kk], BF[jl][kk], acc[(MH) * 4 + il][(NH) * 2 + jl], 0, 0, 0); \
    __builtin_amdgcn_s_setprio(0); \
} while (0)
#define BAR()  __builtin_amdgcn_s_barrier()
#define LGKM0() asm volatile("s_waitcnt lgkmcnt(0)" ::: "memory")

    // prologue: tile0 (A0,B0,B1,A1) + A0(1),B1(1),A1(1) = 14 GLLs
    STAGE_A(0, 0, 0);
    STAGE_B(0, 0, 0);
    STAGE_B(0, 1, 0);
    STAGE_A(0, 1, 0);
    STAGE_A(1, 0, 1);
    STAGE_B(1, 1, 1);
    STAGE_A(1, 1, 1);
    asm volatile("s_waitcnt vmcnt(6)" ::: "memory");   // tile0 landed; 6 in flight
    BAR();
    // pre-issue ph1(t=0) operands
    LOAD_A(0, 0);
    LOAD_B(0, 0, bf0v);

#pragma unroll 2
    for (int t = 0; t < NKT; ++t) {
        const int cb = t & 1;
        const int t1 = (t + 1 < NKT) ? t + 1 : NKT - 1;   // clamped tail: keeps
        const int t2 = (t + 2 < NKT) ? t + 2 : NKT - 1;   // vmcnt counts uniform
        // ---- phase 1: Q(0,0) ----
        BAR();
        LGKM0();
        STAGE_B(cb ^ 1, 0, t1);
        MFMAQ(0, 0, bf0v);
        LOAD_B(cb, 1, bf1v);           // read-ahead for ph2
        // ---- phase 2: Q(0,1) ----
        BAR();
        LGKM0();
        STAGE_A(cb, 0, t2);
        MFMAQ(0, 1, bf1v);
        LOAD_A(cb, 1);                 // read-ahead for ph3
        // ---- phase 3: Q(1,0) ----
        BAR();
        LGKM0();
        STAGE_B(cb, 1, t2);
        MFMAQ(1, 0, bf0v);
        // ---- phase 4: Q(1,1) ----
        asm volatile("s_waitcnt vmcnt(4)" ::: "memory");  // retires through B0(t+1)
        BAR();
        STAGE_A(cb, 1, t2);
        MFMAQ(1, 1, bf1v);
        LOAD_A(cb ^ 1, 0);             // read-ahead for next tile's ph1
        LOAD_B(cb ^ 1, 0, bf0v);
    }
    asm volatile("s_waitcnt vmcnt(0) lgkmcnt(0)" ::: "memory");  // drain tail

    // epilogue
#pragma unroll
    for (int i = 0; i < 8; ++i) {
        const int row0 = tileM + (i >> 2) * 128 + wave_m * 64 + (i & 3) * 16 + quad * 4;
#pragma unroll
        for (int j = 0; j < 4; ++j) {
            const int col = tileN + (j >> 1) * 128 + wave_n * 32 + (j & 1) * 16 + r16;
            const float bv = bias[col];
#pragma unroll
            for (int r = 0; r < 4; ++r) {
                float v = acc[i][j][r] + bv;
                if (EPI == 0) {
                    ((unsigned short*)Cp)[(size_t)(row0 + r) * N + col] = f2bf(v);
                } else {
                    ((float*)Cp)[(size_t)(row0 + r) * N + col] = fmaxf(v, 0.0f);
                }
            }
        }
    }
#undef GLL
#undef STAGE_A
#undef STAGE_B
#undef LOAD_A
#undef LOAD_B
#undef MFMAQ
#undef BAR
#undef LGKM0
}

// ---------------- ONE-PASS scan: decoupled flag-wait, NO grid sync ----------
// Grid (DD/256, SS, BB) = 1024 blocks x 256 thr. Plain launch (not coop).
// Runtime-gated: requires occupancy >= 4 blocks/CU (=> ALL 1024 blocks
// co-resident -> spin-wait is deadlock-free regardless of dispatch order)
// AND localSizeBytes == 0 (no spill; r7/r8 showed this_grid().sync()'s call
// site forces w[] to scratch — a plain inlined spin loop must not).
//
// Per block (channel range, chunk c, batch b):
//   1) load chunk's TT=64 packed bf16 words into registers (w[64])
//   2) local scan -> chunk-end; publish as u64 agent-atomic; fence;
//      __syncthreads; thread0 release-stores flag[chain][c]=1
//   3) wait for flags of ALL j<c (batched 8-wide polls, lane0 spins with
//      s_sleep); then combine predecessors' local ends with running
//      Lambda = lambda^TT weights (8 independent payload loads per round,
//      serial VALU combine) -> carry. No serial block chain: every block
//      resolves its carry directly from the published local ends.
//   4) rescan from register-held w with carry; store packed (re,im) uint
//      (interleaved K-layout matching WoP).
__global__ __launch_bounds__(256, 4)
void scan_onepass(const unsigned short* __restrict__ u,
                  const float* __restrict__ plog,
                  unsigned long long* __restrict__ Epub,
                  int* __restrict__ flags,
                  unsigned short* __restrict__ xr) {
    const int d = blockIdx.x * 256 + threadIdx.x;
    const int c = blockIdx.y, b = blockIdx.z;
    const int chain = b * (DD / 256) + blockIdx.x;    // 0..15

    // ---- load chunk into registers ----
    unsigned int w[TT];
    {
        const unsigned short* up = u + (size_t)(b * LL + c * TT) * (2 * DD) + 2 * d;
#pragma unroll
        for (int tl = 0; tl < TT; ++tl) { w[tl] = *(const unsigned int*)up; up += 2 * DD; }
    }
    const float v  = expf(plog[d]);
    const float th = expf(plog[DD + d]);
    const float g  = expf(plog[2 * DD + d]);
    const float a  = expf(-v);
    const float lr = a * cosf(th), li = a * sinf(th);
    const float aT = expf(-(float)TT * v);
    const float Lr = aT * cosf((float)TT * th), Li = aT * sinf((float)TT * th);

    // ---- phase A: local scan + publish ----
    {
        float zr = 0.f, zi = 0.f;
#pragma unroll
        for (int tl = 0; tl < TT; ++tl) {
            float xv = bf2f((unsigned short)(w[tl] & 0xffffu));
            float yv = bf2f((unsigned short)(w[tl] >> 16));
            float t = lr * zr - li * zi + xv;
            zi = lr * zi + li * zr + yv;
            zr = t;
        }
        unsigned long long q = (unsigned long long)__float_as_uint(zr) |
                               ((unsigned long long)__float_as_uint(zi) << 32);
        __hip_atomic_store(&Epub[(size_t)c * (BB * DD) + b * DD + d], q,
                           __ATOMIC_RELAXED, __HIP_MEMORY_SCOPE_AGENT);
    }
    __threadfence();
    __syncthreads();
    if (threadIdx.x == 0)
        __hip_atomic_store(&flags[chain * SS + c], 1,
                           __ATOMIC_RELEASE, __HIP_MEMORY_SCOPE_AGENT);

    // ---- phase B: wait for predecessors, combine carry ----
    float yr = 0.f, yi = 0.f;
    if (c > 0) {
        const int fbase = chain * SS;
        if ((threadIdx.x & 63) == 0) {                 // one spinner per wave
            for (int j0 = 0; j0 < c; j0 += 8) {
                for (;;) {
                    int got = 0;
#pragma unroll
                    for (int k = 0; k < 8; ++k) {
                        got += (j0 + k >= c) ? 1 :
                            (__hip_atomic_load(&flags[fbase + j0 + k],
                                 __ATOMIC_ACQUIRE, __HIP_MEMORY_SCOPE_AGENT) != 0);
                    }
                    if (got == 8) break;
                    __builtin_amdgcn_s_sleep(2);
                }
            }
        }
        // masked-off lanes waited at same PC; payload loads below are agent
        // atomics (read coherence point) issued after flags observed set.
        const size_t pbase = (size_t)b * DD + d;
        int j = 0;
#define PLD(JJ) __hip_atomic_load(&Epub[(size_t)(JJ) * (BB * DD) + pbase], \
                                  __ATOMIC_RELAXED, __HIP_MEMORY_SCOPE_AGENT)
#define COMB(Q) do { \
        float er = __uint_as_float((unsigned int)(Q)); \
        float ei = __uint_as_float((unsigned int)((Q) >> 32)); \
        float t = Lr * yr - Li * yi + er; \
        yi = Lr * yi + Li * yr + ei; \
        yr = t; } while (0)
        for (; j + 8 <= c; j += 8) {
            unsigned long long q0 = PLD(j + 0), q1 = PLD(j + 1);
            unsigned long long q2 = PLD(j + 2), q3 = PLD(j + 3);
            unsigned long long q4 = PLD(j + 4), q5 = PLD(j + 5);
            unsigned long long q6 = PLD(j + 6), q7 = PLD(j + 7);
            COMB(q0); COMB(q1); COMB(q2); COMB(q3);
            COMB(q4); COMB(q5); COMB(q6); COMB(q7);
        }
        for (; j < c; ++j) { unsigned long long q = PLD(j); COMB(q); }
#undef PLD
#undef COMB
    }

    // ---- phase C: rescan from registers with carry, store packed (re,im) ----
    {
        unsigned short* xp = xr + (size_t)(b * LL + c * TT) * (2 * DD) + 2 * d;
#pragma unroll
        for (int tl = 0; tl < TT; ++tl) {
            float xv = bf2f((unsigned short)(w[tl] & 0xffffu));
            float yv = bf2f((unsigned short)(w[tl] >> 16));
            float t = lr * yr - li * yi + xv;
            yi = lr * yi + li * yr + yv;
            yr = t;
            *(unsigned int*)xp = (unsigned int)f2bf(g * yr) |
                                 ((unsigned int)f2bf(g * yi) << 16);
            xp += 2 * DD;
        }
    }
}

// ---------------- fallback 3-pass scan (proven path) -------------------------
__global__ __launch_bounds__(256)
void scanA(const unsigned short* __restrict__ u,
           const float* __restrict__ plog,
           float2* __restrict__ Eend) {
    const int d = blockIdx.x * 256 + threadIdx.x;
    const int c = blockIdx.y, b = blockIdx.z;
    const float v  = expf(plog[d]);
    const float th = expf(plog[DD + d]);
    const float a  = expf(-v);
    const float lr = a * cosf(th), li = a * sinf(th);
    float zr = 0.f, zi = 0.f;
    const unsigned short* up = u + (size_t)(b * LL + c * TT) * (2 * DD) + 2 * d;
#pragma unroll 8
    for (int tl = 0; tl < TT; ++tl) {
        unsigned int pr = *(const unsigned int*)up;
        float xr = bf2f((unsigned short)(pr & 0xffffu));
        float xi = bf2f((unsigned short)(pr >> 16));
        float t = lr * zr - li * zi + xr;
        zi = lr * zi + li * zr + xi;
        zr = t;
        up += 2 * DD;
    }
    Eend[(size_t)c * (BB * DD) + b * DD + d] = make_float2(zr, zi);
}

__global__ __launch_bounds__(256)
void scanB(const float* __restrict__ plog, float2* __restrict__ E) {
    const int i = blockIdx.x * 256 + threadIdx.x;   // i = b*DD + d
    const int d = i & (DD - 1);
    const float v  = expf(plog[d]);
    const float th = expf(plog[DD + d]);
    const float aT = expf(-(float)TT * v);
    const float Lr = aT * cosf((float)TT * th), Li = aT * sinf((float)TT * th);
    float yr = 0.f, yi = 0.f;
    float2* p = E + i;
#pragma unroll 8
    for (int c = 0; c < SS; ++c) {
        float2 e = *p;
        *p = make_float2(yr, yi);
        float t = Lr * yr - Li * yi + e.x;
        yi = Lr * yi + Li * yr + e.y;
        yr = t;
        p += BB * DD;
    }
}

__global__ __launch_bounds__(256)
void scanC(const unsigned short* __restrict__ u,
           const float* __restrict__ plog,
           const float2* __restrict__ Carry,
           unsigned short* __restrict__ xr) {
    const int d = blockIdx.x * 256 + threadIdx.x;
    const int c = blockIdx.y, b = blockIdx.z;
    const float v  = expf(plog[d]);
    const float th = expf(plog[DD + d]);
    const float g  = expf(plog[2 * DD + d]);
    const float a  = expf(-v);
    const float lr = a * cosf(th), li = a * sinf(th);
    const float2 cy = Carry[(size_t)c * (BB * DD) + b * DD + d];
    float yr = cy.x, yi = cy.y;
    const unsigned short* up = u + (size_t)(b * LL + c * TT) * (2 * DD) + 2 * d;
    unsigned short* xp = xr + (size_t)(b * LL + c * TT) * (2 * DD) + 2 * d;
#pragma unroll 8
    for (int tl = 0; tl < TT; ++tl) {
        unsigned int pr = *(const unsigned int*)up;
        float xrv = bf2f((unsigned short)(pr & 0xffffu));
        float xiv = bf2f((unsigned short)(pr >> 16));
        float t = lr * yr - li * yi + xrv;
        yi = lr * yi + li * yr + xiv;
        yr = t;
        *(unsigned int*)xp = (unsigned int)f2bf(g * yr) |
                             ((unsigned int)f2bf(g * yi) << 16);
        up += 2 * DD;
        xp += 2 * DD;
    }
}

extern "C" void kernel_launch(void* const* d_in, const int* in_sizes, int n_in,
                              void* d_out, int out_size, void* d_ws, size_t ws_size,
                              hipStream_t stream) {
    const float* inputs = (const float*)d_in[0];   // B*L*D = 16777216
    const float* Wi     = (const float*)d_in[1];   // 2D*D  = 2097152
    const float* bi     = (const float*)d_in[2];   // 2D
    const float* Wo     = (const float*)d_in[3];   // D*2D  = 2097152
    const float* bo     = (const float*)d_in[4];   // D
    const float* plog   = (const float*)d_in[5];   // 3*D
    float* out = (float*)d_out;

    const size_t M = (size_t)BB * LL;              // 16384
    unsigned short* u_bf  = (unsigned short*)d_ws;             // M*2D bf16  (64 MB)
    unsigned short* xr_bf = u_bf  + M * 2 * DD;                // M*2D bf16  (64 MB)
    unsigned short* in_bf = xr_bf + M * 2 * DD;                // M*D  bf16  (32 MB)
    unsigned short* Wi_bf = in_bf + M * DD;                    // 2D*D bf16  (4 MB)
    unsigned short* Wo_bf = Wi_bf + (size_t)2 * DD * DD;       // D*2D bf16  (4 MB)
    // Epub/Eend (SS*B*D x8B = 2 MB) aliases in_bf (dead after GEMM1).
    unsigned long long* Epub = (unsigned long long*)in_bf;
    float2* Eend = (float2*)in_bf;
    // flags (NCH*SS ints = 4 KB) after Wo_bf (region already used in r0-r2).
    int* flags = (int*)(Wo_bf + (size_t)2 * DD * DD);

    // merged bf16 casts (+ flag zeroing) in one dispatch
    {
        int total = NIN4 + NWI4 + NWO8;            // 4980736, divisible by 256
        cast_all_kernel<<<total / 256, 256, 0, stream>>>(
            (const float4*)inputs, (ushort4*)in_bf,
            (const float4*)Wi,     (ushort4*)Wi_bf,
            Wo,                    Wo_bf,
            flags);
    }

    // GEMM1: u[M, 2D] = in_bf[M, D] @ Wi^T + bi   (bf16 out), N=2048 -> NT=8
    gemm256<DD, 8, 0><<<(M / 256) * 8, 512, 0, stream>>>(
        in_bf, Wi_bf, bi, (void*)u_bf);

    // scan: one-pass (flag-wait) if provably safe; else proven 3-pass.
    // Safety gates (cached): (a) >=4 blocks/CU -> all 1024 blocks co-resident
    // -> spin-wait deadlock-free under ANY dispatch order; (b) no scratch
    // (localSizeBytes==0) -> w[] really is register-resident (r7/r8 alarm).
    static int onepass_ok = -1;
    if (onepass_ok < 0) {
        int nb = 0;
        hipError_t qe = hipOccupancyMaxActiveBlocksPerMultiprocessor(
            &nb, (const void*)scan_onepass, 256, 0);
        hipFuncAttributes attr{};
        hipError_t ae = hipFuncGetAttributes(&attr, (const void*)scan_onepass);
        onepass_ok = (qe == hipSuccess && nb >= 4 &&
                      ae == hipSuccess && attr.localSizeBytes == 0) ? 1 : 0;
    }
    if (onepass_ok) {
        scan_onepass<<<dim3(DD / 256, SS, BB), 256, 0, stream>>>(
            u_bf, plog, Epub, flags, xr_bf);
    } else {
        scanA<<<dim3(DD / 256, SS, BB), 256, 0, stream>>>(u_bf, plog, Eend);
        scanB<<<(BB * DD) / 256, 256, 0, stream>>>(plog, Eend);
        scanC<<<dim3(DD / 256, SS, BB), 256, 0, stream>>>(u_bf, plog, Eend, xr_bf);
    }

    // GEMM2: out[M, D] = relu(xr[M, 2D] @ WoP^T + bo)  (f32 out), N=1024 -> NT=4
    gemm256<2 * DD, 4, 1><<<(M / 256) * 4, 512, 0, stream>>>(
        xr_bf, Wo_bf, bo, (void*)out);
}